// Round 17
// baseline (650.906 us; speedup 1.0000x reference)
//
#include <hip/hip_runtime.h>
#include <cstdint>
#include <cstddef>

// Problem constants (fixed by the reference)
#define NB 4
#define NS 1024
#define ND 1024
#define NH 16
#define NDH 64
#define NP 112
#define NTOPK 64
#define NZCAP 128   // per-row compacted nonzero capacity
#define PCH 14      // splats per phi chunk (8 chunks)

typedef _Float16 f16x8 __attribute__((ext_vector_type(8)));
typedef short bf16x8 __attribute__((ext_vector_type(8)));
typedef float f32x4 __attribute__((ext_vector_type(4)));
typedef unsigned short u16x8 __attribute__((ext_vector_type(8)));

// RNE float -> bf16 bits
__device__ __forceinline__ unsigned short bf16r(float f) {
  const unsigned u = __float_as_uint(f);
  return (unsigned short)((u + 0x7FFFu + ((u >> 16) & 1u)) >> 16);
}

// ---------------------------------------------------------------------------
// prep v4: fp64 Cholesky, transposed LDS layout A2[e][t] = A[t][e], trailing
// update parallelized across 4 waves (j strided by q). Bitwise-identical
// fp64 ops in identical k-order. (validated round 16)
// ---------------------------------------------------------------------------
__global__ __launch_bounds__(256) void prep_kernel(
    const float* __restrict__ mu, const float* __restrict__ prec,
    const float* __restrict__ spw, _Float16* __restrict__ Rh,
    _Float16* __restrict__ Rl, float* __restrict__ tneg,
    float* __restrict__ lswg) {
  __shared__ double A2[64][64];  // 32 KB, A2[e][t] = A[t][e]
  const int p = blockIdx.x;
  const int t = threadIdx.x & 63, q = threadIdx.x >> 6;

  for (int e = q; e < 64; e += 4)
    A2[e][t] = (double)prec[((size_t)p * 64 + e) * 64 + t];  // symmetric read
  __syncthreads();

  for (int k = 0; k < 64; ++k) {
    if (threadIdx.x == k) A2[k][k] = sqrt(A2[k][k]);
    __syncthreads();
    if (q == 0 && t > k) A2[k][t] /= A2[k][k];
    __syncthreads();
    const double lik = A2[k][t];  // meaningful only for t > k (loop guards)
    for (int j = k + 1 + q; j <= t; j += 4)
      A2[j][t] -= lik * A2[k][j];  // distinct (j,t) per thread; reads row k
    __syncthreads();
  }

  for (int d = q; d < 64; d += 4) {
    const float rv = (t >= d) ? (float)A2[d][t] : 0.f;
    const _Float16 h = (_Float16)rv;
    Rh[((size_t)p << 12) + (d << 6) + t] = h;
    Rl[((size_t)p << 12) + (d << 6) + t] =
        (_Float16)((rv - (float)h) * 2048.0f);
  }

  if (q == 0) {
    double s = 0.0;
    for (int e = t; e < 64; ++e) s += A2[t][e] * (double)mu[p * 64 + e];
    tneg[p * 64 + t] = (float)(-s);
  }
  if (threadIdx.x == 0) lswg[p] = 0.5f * logf(spw[p]);
}

// ---------------------------------------------------------------------------
// split_x: fp32 -> fp16 hi + (lo * 2048), elementwise (8 elems/thread)
// ---------------------------------------------------------------------------
__global__ __launch_bounds__(256) void split_x(
    const float* __restrict__ X, _Float16* __restrict__ Xh,
    _Float16* __restrict__ Xl) {
  const size_t i = ((size_t)blockIdx.x * 256 + threadIdx.x) * 8;
  const float4 a = *(const float4*)(X + i);
  const float4 b = *(const float4*)(X + i + 4);
  const float v[8] = {a.x, a.y, a.z, a.w, b.x, b.y, b.z, b.w};
  f16x8 hv, lv;
#pragma unroll
  for (int j = 0; j < 8; ++j) {
    const _Float16 h = (_Float16)v[j];
    hv[j] = h;
    lv[j] = (_Float16)((v[j] - (float)h) * 2048.0f);
  }
  *(f16x8*)(Xh + i) = hv;
  *(f16x8*)(Xl + i) = lv;
}

// ---------------------------------------------------------------------------
// transpose_split: W[k][n] fp32 (1024x1024) -> Th/Tl [n][k] fp16 split
// ---------------------------------------------------------------------------
__global__ __launch_bounds__(256) void transpose_split(
    const float* __restrict__ W, _Float16* __restrict__ Th,
    _Float16* __restrict__ Tl) {
  __shared__ float T[64][65];
  const int tid = threadIdx.x;
  const int k0 = blockIdx.x * 64, n0 = blockIdx.y * 64;
  const int c = tid & 63, rb = tid >> 6;
#pragma unroll 4
  for (int i = 0; i < 16; ++i) {
    const int r = rb * 16 + i;
    T[r][c] = W[(size_t)(k0 + r) * 1024 + n0 + c];
  }
  __syncthreads();
#pragma unroll 4
  for (int i = 0; i < 16; ++i) {
    const int r = rb * 16 + i;               // local n
    const float v = T[c][r];                 // = W[k0+c][n0+r]
    const _Float16 h = (_Float16)v;
    Th[(size_t)(n0 + r) * 1024 + k0 + c] = h;
    Tl[(size_t)(n0 + r) * 1024 + k0 + c] = (_Float16)((v - (float)h) * 2048.0f);
  }
}

// ---------------------------------------------------------------------------
// transpose_h: W[k][n] fp32 -> Th [n][k] fp16 (hi plane only)
// ---------------------------------------------------------------------------
__global__ __launch_bounds__(256) void transpose_h(
    const float* __restrict__ W, _Float16* __restrict__ Th) {
  __shared__ float T[64][65];
  const int tid = threadIdx.x;
  const int k0 = blockIdx.x * 64, n0 = blockIdx.y * 64;
  const int c = tid & 63, rb = tid >> 6;
#pragma unroll 4
  for (int i = 0; i < 16; ++i) {
    const int r = rb * 16 + i;
    T[r][c] = W[(size_t)(k0 + r) * 1024 + n0 + c];
  }
  __syncthreads();
#pragma unroll 4
  for (int i = 0; i < 16; ++i) {
    const int r = rb * 16 + i;
    Th[(size_t)(n0 + r) * 1024 + k0 + c] = (_Float16)T[c][r];
  }
}

// ---------------------------------------------------------------------------
// gemmq_mfma: Q = (hs @ Wq + bq) * 0.125 via fp16-split MFMA (hh + hl + lh),
// output fp16-split Qh/Ql in [bh][s][d] layout. (validated round 6)
// ---------------------------------------------------------------------------
__global__ __launch_bounds__(256, 2) void gemmq_mfma(
    const _Float16* __restrict__ Xh, const _Float16* __restrict__ Xl,
    const _Float16* __restrict__ Wth, const _Float16* __restrict__ Wtl,
    const float* __restrict__ bias, _Float16* __restrict__ QhO,
    _Float16* __restrict__ QlO) {
  const int tid = threadIdx.x, lane = tid & 63, wv = tid >> 6;
  const int l15 = lane & 15, lhi = lane >> 4;
  const int n0 = blockIdx.x * 64;
  const int m0 = blockIdx.y * 128 + wv * 32;

  f32x4 aM[2][4], aC[2][4];
#pragma unroll
  for (int i = 0; i < 2; ++i)
#pragma unroll
    for (int j = 0; j < 4; ++j) {
      const f32x4 z = {0.f, 0.f, 0.f, 0.f};
      aM[i][j] = z; aC[i][j] = z;
    }

  const _Float16* xh0 = Xh + (size_t)(m0 + l15) * 1024 + lhi * 8;
  const _Float16* xl0 = Xl + (size_t)(m0 + l15) * 1024 + lhi * 8;
  const _Float16* wh0 = Wth + (size_t)(n0 + l15) * 1024 + lhi * 8;
  const _Float16* wl0 = Wtl + (size_t)(n0 + l15) * 1024 + lhi * 8;

#pragma unroll 4
  for (int k0 = 0; k0 < 1024; k0 += 32) {
    f16x8 ah[2], al[2], bh[4], bl[4];
#pragma unroll
    for (int mA = 0; mA < 2; ++mA) {
      ah[mA] = *(const f16x8*)(xh0 + mA * 16384 + k0);
      al[mA] = *(const f16x8*)(xl0 + mA * 16384 + k0);
    }
#pragma unroll
    for (int nB = 0; nB < 4; ++nB) {
      bh[nB] = *(const f16x8*)(wh0 + nB * 16384 + k0);
      bl[nB] = *(const f16x8*)(wl0 + nB * 16384 + k0);
    }
#pragma unroll
    for (int mA = 0; mA < 2; ++mA)
#pragma unroll
      for (int nB = 0; nB < 4; ++nB) {
        aM[mA][nB] = __builtin_amdgcn_mfma_f32_16x16x32_f16(ah[mA], bh[nB], aM[mA][nB], 0, 0, 0);
        aC[mA][nB] = __builtin_amdgcn_mfma_f32_16x16x32_f16(ah[mA], bl[nB], aC[mA][nB], 0, 0, 0);
        aC[mA][nB] = __builtin_amdgcn_mfma_f32_16x16x32_f16(al[mA], bh[nB], aC[mA][nB], 0, 0, 0);
      }
  }

  const float eps = 4.8828125e-4f;  // 2^-11
  const int h = n0 >> 6;
  float bq[4];
#pragma unroll
  for (int nB = 0; nB < 4; ++nB) bq[nB] = bias[n0 + nB * 16 + l15];
#pragma unroll
  for (int mA = 0; mA < 2; ++mA)
#pragma unroll
    for (int nB = 0; nB < 4; ++nB) {
      const int dd = nB * 16 + l15;
#pragma unroll
      for (int r = 0; r < 4; ++r) {
        const int m = m0 + mA * 16 + lhi * 4 + r;
        const int b = m >> 10, s = m & 1023;
        const float v = (aM[mA][nB][r] + aC[mA][nB][r] * eps + bq[nB]) * 0.125f;
        const _Float16 hh = (_Float16)v;
        const size_t o = ((((size_t)b * NH + h) << 10) + s) * 64 + dd;
        QhO[o] = hh;
        QlO[o] = (_Float16)((v - (float)hh) * 2048.0f);
      }
    }
}

// ---------------------------------------------------------------------------
// gemmv_mfma: V-half = hs @ Wv + bv via fp16 MFMA (A converted in-register
// RNE, B single fp16 plane). fp32 output, head-split [lbh][s][64].
// ---------------------------------------------------------------------------
__global__ __launch_bounds__(256, 2) void gemmv_mfma(
    const float* __restrict__ X, const _Float16* __restrict__ Wth,
    const float* __restrict__ bias, float* __restrict__ dst,
    int moff, int bh0) {
  const int tid = threadIdx.x, lane = tid & 63, wv = tid >> 6;
  const int l15 = lane & 15, lhi = lane >> 4;
  const int n0 = blockIdx.x * 64;
  const int m0 = moff + blockIdx.y * 128 + wv * 32;

  f32x4 acc[2][4];
#pragma unroll
  for (int i = 0; i < 2; ++i)
#pragma unroll
    for (int j = 0; j < 4; ++j) {
      const f32x4 z = {0.f, 0.f, 0.f, 0.f};
      acc[i][j] = z;
    }

  const float* x0 = X + (size_t)(m0 + l15) * 1024 + lhi * 8;
  const _Float16* w0 = Wth + (size_t)(n0 + l15) * 1024 + lhi * 8;

#pragma unroll 4
  for (int k0 = 0; k0 < 1024; k0 += 32) {
    f16x8 ah[2], bh[4];
#pragma unroll
    for (int mA = 0; mA < 2; ++mA) {
      const float4 a = *(const float4*)(x0 + mA * 16384 + k0);
      const float4 b = *(const float4*)(x0 + mA * 16384 + k0 + 4);
      f16x8 hv;
      hv[0] = (_Float16)a.x; hv[1] = (_Float16)a.y;
      hv[2] = (_Float16)a.z; hv[3] = (_Float16)a.w;
      hv[4] = (_Float16)b.x; hv[5] = (_Float16)b.y;
      hv[6] = (_Float16)b.z; hv[7] = (_Float16)b.w;
      ah[mA] = hv;
    }
#pragma unroll
    for (int nB = 0; nB < 4; ++nB)
      bh[nB] = *(const f16x8*)(w0 + nB * 16384 + k0);
#pragma unroll
    for (int mA = 0; mA < 2; ++mA)
#pragma unroll
      for (int nB = 0; nB < 4; ++nB)
        acc[mA][nB] = __builtin_amdgcn_mfma_f32_16x16x32_f16(
            ah[mA], bh[nB], acc[mA][nB], 0, 0, 0);
  }

  const int h = n0 >> 6;
  float bb[4];
#pragma unroll
  for (int nB = 0; nB < 4; ++nB) bb[nB] = bias[n0 + nB * 16 + l15];
#pragma unroll
  for (int mA = 0; mA < 2; ++mA)
#pragma unroll
    for (int nB = 0; nB < 4; ++nB) {
      const int dd = nB * 16 + l15;
#pragma unroll
      for (int r = 0; r < 4; ++r) {
        const int m = m0 + mA * 16 + lhi * 4 + r;
        const int bidx = m >> 10, s = m & 1023;
        const int lbh = (bidx << 4) + h - bh0;
        dst[((((size_t)lbh << 10) + s) << 6) + dd] = acc[mA][nB][r] + bb[nB];
      }
    }
}

// ---------------------------------------------------------------------------
// phi v3 (log-domain): ls = 0.5*log(w) - 0.5*||R q + tneg||^2 via MFMA,
// R double-buffered in LDS (XOR-swizzle both sides). Writes Lt[bh][p][s].
// ---------------------------------------------------------------------------
__global__ __launch_bounds__(256, 2) void phi3(
    const _Float16* __restrict__ Qh, const _Float16* __restrict__ Ql,
    const _Float16* __restrict__ Rh, const _Float16* __restrict__ Rl,
    const float* __restrict__ tneg, const float* __restrict__ lswg,
    float* __restrict__ Lt) {
  __shared__ __align__(16) _Float16 RhS[2][4096];
  __shared__ __align__(16) _Float16 RlS[2][4096];
  __shared__ __align__(16) float tns[PCH * 64];
  __shared__ float lsws[PCH];
  const int tid = threadIdx.x, lane = tid & 63, wv = tid >> 6;
  const int l15 = lane & 15, lhi = lane >> 4;
  const int tokbase = blockIdx.x * 256;
  const int tb = tokbase + wv * 64;
  const int pbase = blockIdx.y * PCH;
  const float eps = 4.8828125e-4f;

  for (int i = tid; i < PCH * 16; i += 256)
    ((float4*)tns)[i] = ((const float4*)(tneg + (pbase << 6)))[i];
  if (tid < PCH) lsws[tid] = lswg[pbase + tid];

  f16x8 qb[4][2][2];
#pragma unroll
  for (int T = 0; T < 4; ++T)
#pragma unroll
    for (int c = 0; c < 2; ++c) {
      const size_t off = ((size_t)(tb + T * 16 + l15) << 6) + c * 32 + lhi * 8;
      qb[T][c][0] = *(const f16x8*)(Qh + off);
      qb[T][c][1] = *(const f16x8*)(Ql + off);
    }

  f16x8 sgH[2], sgL[2];
#define PHI_LOAD(p)                                                          \
  {                                                                          \
    const _Float16* rhp = Rh + ((size_t)(pbase + (p)) << 12);                \
    const _Float16* rlp = Rl + ((size_t)(pbase + (p)) << 12);                \
    _Pragma("unroll") for (int j = 0; j < 2; ++j) {                          \
      const int X = tid * 32 + j * 16;                                       \
      const int src = X ^ (((X >> 7) & 7) << 4);                             \
      sgH[j] = *(const f16x8*)((const char*)rhp + src);                      \
      sgL[j] = *(const f16x8*)((const char*)rlp + src);                      \
    }                                                                        \
  }
#define PHI_WRITE(buf)                                                       \
  {                                                                          \
    _Pragma("unroll") for (int j = 0; j < 2; ++j) {                          \
      const int X = tid * 32 + j * 16;                                       \
      *(f16x8*)((char*)&RhS[buf][0] + X) = sgH[j];                           \
      *(f16x8*)((char*)&RlS[buf][0] + X) = sgL[j];                           \
    }                                                                        \
  }

  PHI_LOAD(0)
  PHI_WRITE(0)

  float* ub = Lt + (((size_t)(tokbase >> 10) * NP) << 10);
  const int sbase = (tb & 1023);

  for (int pi = 0; pi < PCH; ++pi) {
    __syncthreads();
    const int buf = pi & 1;
    if (pi + 1 < PCH) PHI_LOAD(pi + 1)

    float sq0 = 0.f, sq1 = 0.f, sq2 = 0.f, sq3 = 0.f;
#pragma unroll
    for (int mt = 0; mt < 4; ++mt) {
      const float4 tv = *(const float4*)&tns[(pi << 6) + mt * 16 + lhi * 4];
      const f32x4 ti = {tv.x, tv.y, tv.z, tv.w};
      const f32x4 z = {0.f, 0.f, 0.f, 0.f};
      f32x4 aM[4], aC[4];
#pragma unroll
      for (int T = 0; T < 4; ++T) { aM[T] = ti; aC[T] = z; }
#pragma unroll
      for (int c = 0; c < 2; ++c) {
        if (mt >= 2 && c == 0) continue;  // upper-tri zero block
        const int row = mt * 16 + l15;
        int bo = row * 128 + c * 64 + lhi * 16;
        bo ^= ((row & 7) << 4);
        const f16x8 ah = *(const f16x8*)((const char*)&RhS[buf][0] + bo);
        const f16x8 al = *(const f16x8*)((const char*)&RlS[buf][0] + bo);
#pragma unroll
        for (int T = 0; T < 4; ++T) {
          aM[T] = __builtin_amdgcn_mfma_f32_16x16x32_f16(ah, qb[T][c][0], aM[T], 0, 0, 0);
          aC[T] = __builtin_amdgcn_mfma_f32_16x16x32_f16(ah, qb[T][c][1], aC[T], 0, 0, 0);
          aC[T] = __builtin_amdgcn_mfma_f32_16x16x32_f16(al, qb[T][c][0], aC[T], 0, 0, 0);
        }
      }
#pragma unroll
      for (int r = 0; r < 4; ++r) {
        float y;
        y = aM[0][r] + aC[0][r] * eps; sq0 += y * y;
        y = aM[1][r] + aC[1][r] * eps; sq1 += y * y;
        y = aM[2][r] + aC[2][r] * eps; sq2 += y * y;
        y = aM[3][r] + aC[3][r] * eps; sq3 += y * y;
      }
    }
    sq0 += __shfl_xor(sq0, 16, 64); sq0 += __shfl_xor(sq0, 32, 64);
    sq1 += __shfl_xor(sq1, 16, 64); sq1 += __shfl_xor(sq1, 32, 64);
    sq2 += __shfl_xor(sq2, 16, 64); sq2 += __shfl_xor(sq2, 32, 64);
    sq3 += __shfl_xor(sq3, 16, 64); sq3 += __shfl_xor(sq3, 32, 64);
    const float sqs = (lhi == 0) ? sq0 : (lhi == 1) ? sq1 : (lhi == 2) ? sq2 : sq3;
    ub[((size_t)(pbase + pi) << 10) + sbase + lane] = lsws[pi] - 0.5f * sqs;

    __syncthreads();
    if (pi + 1 < PCH) PHI_WRITE(buf ^ 1)
  }
#undef PHI_LOAD
#undef PHI_WRITE
}

// ---------------------------------------------------------------------------
// psi v3: 64 tokens x 4 splat-groups per block (512 blocks/half). ls held in
// 28 registers, one expf pass, TWO exact bf16 planes. LDS-staged coalesced
// u16x8 write-out to token-major [lbh][s][112].
// ---------------------------------------------------------------------------
__global__ __launch_bounds__(256) void psi_kernel(
    const float* __restrict__ Lt, unsigned short* __restrict__ P0,
    unsigned short* __restrict__ P1, float* __restrict__ af, int bh0) {
  __shared__ unsigned short Ls[2][64 * 120];  // 30 KB
  __shared__ float pmax[4][64];
  const int tid = threadIdx.x;
  const int lbh = blockIdx.x >> 4;
  const int gbh = bh0 + lbh;
  const int s0 = (blockIdx.x & 15) << 6;
  const int tok = tid & 63, pg = tid >> 6;

  const float* col = Lt + ((size_t)gbh * NP + pg * 28) * 1024 + s0 + tok;
  float ls[28];
  float a = -3.4e38f;
#pragma unroll
  for (int j = 0; j < 28; ++j) {
    ls[j] = col[(size_t)j << 10];
    a = fmaxf(a, ls[j]);
  }
  pmax[pg][tok] = a;
  __syncthreads();
  a = fmaxf(fmaxf(pmax[0][tok], pmax[1][tok]),
            fmaxf(pmax[2][tok], pmax[3][tok]));
  if (pg == 0) af[(gbh << 10) + s0 + tok] = a;

  const int rbase = tok * 120 + pg * 28;
#pragma unroll
  for (int jj = 0; jj < 14; ++jj) {
    unsigned short v0[2], v1[2];
#pragma unroll
    for (int e = 0; e < 2; ++e) {
      const float x = expf(ls[jj * 2 + e] - a);
      const unsigned short b0 = bf16r(x);
      const float f0 = __uint_as_float((unsigned)b0 << 16);
      const unsigned short b1 = bf16r((x - f0) * 256.0f);  // exact residual
      if (e == 0) { v0[0] = b0; v0[1] = b1; }
      else        { v1[0] = b0; v1[1] = b1; }
    }
#pragma unroll
    for (int pl = 0; pl < 2; ++pl) {
      ushort2 pk; pk.x = v0[pl]; pk.y = v1[pl];
      *(ushort2*)&Ls[pl][rbase + jj * 2] = pk;
    }
  }
  __syncthreads();

  // coalesced write-out: 896 u16x8 per plane
  const size_t gb = (size_t)((lbh << 10) + s0) * NP;
#pragma unroll 1
  for (int pl = 0; pl < 2; ++pl) {
    unsigned short* dst = (pl == 0 ? P0 : P1) + gb;
    const unsigned short* src = &Ls[pl][0];
    for (int i = tid; i < 896; i += 256) {
      const int t2 = i / 14;
      const int off = (i - t2 * 14) * 8;
      *(u16x8*)(dst + t2 * 112 + off) = *(const u16x8*)(src + t2 * 120 + off);
    }
  }
}

// G-tile fp16 LDS addressing: in-row XOR swizzle spreads the 4 lhi write
// groups across distinct bank octets; read side uses the same row-uniform XOR.
#define GADDR(row, col) \
  (((row) << 11) + ((((col) << 1) ^ ((((row) >> 2) & 3) << 5))))

// ---------------------------------------------------------------------------
// attn6: round-16 attn4 structure (default launch bounds, NO vgpr cap) with
// the G tile stored fp16 in LDS via GADDR swizzle (40 KB total -> 4
// blocks/CU, 2x latency-hiding waves). fp16-G numerics proven bit-identical
// in round 12 (absmax unchanged). Gram via bf16x2 MFMA with pipelined B
// loads; exact top-64 threshold (bit search from MSB(row max), early exit);
// compact into dead G rows (raw addressing); sparse ctx with 8-wide gather
// batches; ctx fp16 pre-scaled by 2^80.
// XCD-swizzled grid: bhl = ((id>>9)<<3)|(id&7), tile=(id>>3)&63.
// ---------------------------------------------------------------------------
__global__ __launch_bounds__(512) void attn6_kernel(
    const unsigned short* __restrict__ P0, const unsigned short* __restrict__ P1,
    const float* __restrict__ af, const float* __restrict__ V,
    const float* __restrict__ amask, _Float16* __restrict__ ctxh, int bh0) {
  __shared__ __align__(16) _Float16 Ath[16 * 1024];  // 32 KB: G tile fp16
  __shared__ __align__(16) float eajs[1024];         // 4 KB: exp(a_j)
  __shared__ __align__(16) float msks[1024];         // 4 KB: mask row
  const int tid = threadIdx.x;
  const int id = blockIdx.x;
  const int bhl = ((id >> 9) << 3) | (id & 7);   // 0..31 local
  const int gbh = bh0 + bhl;
  const int i0 = ((id >> 3) & 63) * 16;
  const int bidx = gbh >> 4;
  const int h = gbh & 15;
  const int lane = tid & 63, wv = tid >> 6;
  const int l15 = lane & 15, lhi = lane >> 4;
  const float* afb = af + (gbh << 10);
  char* Ab = (char*)Ath;

  eajs[tid] = expf(afb[tid]);
  eajs[tid + 512] = expf(afb[tid + 512]);
  msks[tid] = amask[(bidx << 10) + tid];
  msks[tid + 512] = amask[(bidx << 10) + tid + 512];

  // ---- Gram via bf16x2 MFMA, pipelined B loads, fp16 G store ----
  {
    const unsigned short* Pb0 = P0 + (size_t)(bhl << 10) * NP;
    const unsigned short* Pb1 = P1 + (size_t)(bhl << 10) * NP;
    const bf16x8 zz = {0, 0, 0, 0, 0, 0, 0, 0};
    bf16x8 A0[4], A1[4];
    {
      const size_t ro = (size_t)(i0 + l15) * NP;
#pragma unroll
      for (int c = 0; c < 3; ++c) {
        A0[c] = *(const bf16x8*)(Pb0 + ro + c * 32 + lhi * 8);
        A1[c] = *(const bf16x8*)(Pb1 + ro + c * 32 + lhi * 8);
      }
      A0[3] = (lhi < 2) ? *(const bf16x8*)(Pb0 + ro + 96 + lhi * 8) : zz;
      A1[3] = (lhi < 2) ? *(const bf16x8*)(Pb1 + ro + 96 + lhi * 8) : zz;
    }

#define LOADB(dst, Pb, jtv)                                                  \
  {                                                                          \
    const size_t co = (size_t)((jtv) * 16 + l15) * NP;                       \
    _Pragma("unroll") for (int c = 0; c < 3; ++c)                            \
        dst[c] = *(const bf16x8*)(Pb + co + c * 32 + lhi * 8);               \
    dst[3] = (lhi < 2) ? *(const bf16x8*)(Pb + co + 96 + lhi * 8) : zz;      \
  }

    bf16x8 B0c[4], B1c[4], B0n[4];
    LOADB(B0c, Pb0, wv * 8)
    LOADB(B1c, Pb1, wv * 8)

#pragma unroll 1
    for (int jt8 = 0; jt8 < 8; ++jt8) {
      const int jt = wv * 8 + jt8;
      if (jt8 < 7) LOADB(B0n, Pb0, jt + 1)  // prefetch next hi plane
      f32x4 g0 = {0.f, 0.f, 0.f, 0.f};
      f32x4 g1a = {0.f, 0.f, 0.f, 0.f}, g1b = {0.f, 0.f, 0.f, 0.f};
      __builtin_amdgcn_s_setprio(1);
#pragma unroll
      for (int c = 0; c < 4; ++c) {
        g0  = __builtin_amdgcn_mfma_f32_16x16x32_bf16(A0[c], B0c[c], g0, 0, 0, 0);
        g1a = __builtin_amdgcn_mfma_f32_16x16x32_bf16(A0[c], B1c[c], g1a, 0, 0, 0);
        g1b = __builtin_amdgcn_mfma_f32_16x16x32_bf16(A1[c], B0c[c], g1b, 0, 0, 0);
      }
      __builtin_amdgcn_s_setprio(0);
#pragma unroll
      for (int r = 0; r < 4; ++r) {
        const float g = fmaxf(g0[r] + (g1a[r] + g1b[r]) * 0.00390625f, 0.f);
        *(_Float16*)(Ab + GADDR(lhi * 4 + r, jt * 16 + l15)) = (_Float16)g;
      }
      if (jt8 < 7) {
        LOADB(B1c, Pb1, jt + 1)  // lo plane: hides under next g0 chain
#pragma unroll
        for (int c = 0; c < 4; ++c) B0c[c] = B0n[c];
      }
    }
#undef LOADB
  }
  __syncthreads();

  // ---- per-wave: fv, exact top-64 thr, rowsum->inv, compact, sparse ctx ----
  {
    const float* Vb = V + ((size_t)bhl << 16);
    int cnts[2];

#pragma unroll
    for (int rr = 0; rr < 2; ++rr) {
      const int r = wv * 2 + rr;
      const float eai = expf(afb[i0 + r]);
      float fv[16], fm[16];
      float mx = 0.f;
#pragma unroll
      for (int k = 0; k < 16; ++k) {
        const int j = k * 64 + lane;
        const float gv = (float)*(const _Float16*)(Ab + GADDR(r, j));
        fv[k] = eai * (eajs[j] * gv);
        fm[k] = fv[k] * msks[j];
        mx = fmaxf(mx, fv[k]);
      }
      // wave max -> start bit (skipped candidates all have cnt==0)
#pragma unroll
      for (int off = 32; off > 0; off >>= 1) mx = fmaxf(mx, __shfl_xor(mx, off, 64));
      const unsigned mu = __float_as_uint(mx);
      const int startbit = (mu == 0u) ? 0 : (31 - __clz(mu));
      unsigned c = 0u;
      for (int bit = startbit; bit >= 0; --bit) {
        const unsigned cand = c | (1u << bit);
        int cnt = 0;
#pragma unroll
        for (int k = 0; k < 16; ++k)
          cnt += (int)__popcll(__ballot(__float_as_uint(fv[k]) >= cand));
        if (cnt >= NTOPK) {
          c = cand;
          if (cnt == NTOPK) break;
        }
      }
      const float thr = __uint_as_float(c);
      float ssum = 0.f;
#pragma unroll
      for (int k = 0; k < 16; ++k) ssum += (fv[k] >= thr) ? fm[k] : 0.f;
#pragma unroll
      for (int off = 32; off > 0; off >>= 1) ssum += __shfl_xor(ssum, off, 64);
      const float inv = 1.0f / fmaxf(ssum, 1e-12f);

      // compact into this row's (now dead) G storage: raw addressing
      float* nzv = (float*)(Ab + (r << 11));
      int* nzi = (int*)(Ab + (r << 11) + 512);
      unsigned cnt = 0;
#pragma unroll
      for (int k = 0; k < 16; ++k) {
        const bool keep = (fv[k] >= thr) && (fm[k] > 0.f);
        const unsigned long long b = __ballot(keep);
        if (keep) {
          const unsigned pos = cnt + (unsigned)__popcll(b & ((1ull << lane) - 1ull));
          if (pos < NZCAP) {
            nzi[pos] = k * 64 + lane;
            nzv[pos] = fm[k] * inv;
          }
        }
        cnt += (unsigned)__popcll(b);
      }
      cnts[rr] = (int)(cnt < NZCAP ? cnt : NZCAP);
    }

#pragma unroll
    for (int rr = 0; rr < 2; ++rr) {
      const int r = wv * 2 + rr;
      const float* nzv = (const float*)(Ab + (r << 11));
      const int* nzi = (const int*)(Ab + (r << 11) + 512);
      const int n = cnts[rr];
      float a0 = 0.f, a1 = 0.f, a2 = 0.f, a3 = 0.f;
      int t = 0;
      for (; t + 8 <= n; t += 8) {
        const int j0 = nzi[t], j1 = nzi[t + 1], j2 = nzi[t + 2], j3 = nzi[t + 3];
        const int j4 = nzi[t + 4], j5 = nzi[t + 5], j6 = nzi[t + 6], j7 = nzi[t + 7];
        const float w0 = nzv[t], w1 = nzv[t + 1], w2 = nzv[t + 2], w3 = nzv[t + 3];
        const float w4 = nzv[t + 4], w5 = nzv[t + 5], w6 = nzv[t + 6], w7 = nzv[t + 7];
        const float v0 = Vb[(j0 << 6) + lane];
        const float v1 = Vb[(j1 << 6) + lane];
        const float v2 = Vb[(j2 << 6) + lane];
        const float v3 = Vb[(j3 << 6) + lane];
        const float v4 = Vb[(j4 << 6) + lane];
        const float v5 = Vb[(j5 << 6) + lane];
        const float v6 = Vb[(j6 << 6) + lane];
        const float v7 = Vb[(j7 << 6) + lane];
        a0 += w0 * v0; a1 += w1 * v1; a2 += w2 * v2; a3 += w3 * v3;
        a0 += w4 * v4; a1 += w5 * v5; a2 += w6 * v6; a3 += w7 * v7;
      }
      for (; t < n; ++t) a0 += nzv[t] * Vb[(nzi[t] << 6) + lane];
      const float s = ((a0 + a1) + (a2 + a3)) * 0x1p80f;  // pre-scale 2^80
      ctxh[(size_t)((bidx << 10) + i0 + r) * 1024 + (h << 6) + lane] =
          (_Float16)s;
    }
  }
}

// ---------------------------------------------------------------------------
// gemmo_mfma: out = ctx_f16 @ Wo_split * 2^-80 + bo. A = single fp16 plane.
// ---------------------------------------------------------------------------
__global__ __launch_bounds__(256, 2) void gemmo_mfma(
    const _Float16* __restrict__ Ch, const _Float16* __restrict__ Wth,
    const _Float16* __restrict__ Wtl, const float* __restrict__ bias,
    float* __restrict__ out) {
  const int tid = threadIdx.x, lane = tid & 63, wv = tid >> 6;
  const int l15 = lane & 15, lhi = lane >> 4;
  const int n0 = blockIdx.x * 64;
  const int m0 = blockIdx.y * 128 + wv * 32;

  f32x4 aM[2][4], aC[2][4];
#pragma unroll
  for (int i = 0; i < 2; ++i)
#pragma unroll
    for (int j = 0; j < 4; ++j) {
      const f32x4 z = {0.f, 0.f, 0.f, 0.f};
      aM[i][j] = z; aC[i][j] = z;
    }

  const _Float16* xh0 = Ch + (size_t)(m0 + l15) * 1024 + lhi * 8;
  const _Float16* wh0 = Wth + (size_t)(n0 + l15) * 1024 + lhi * 8;
  const _Float16* wl0 = Wtl + (size_t)(n0 + l15) * 1024 + lhi * 8;

#pragma unroll 4
  for (int k0 = 0; k0 < 1024; k0 += 32) {
    f16x8 ah[2], bh[4], bl[4];
#pragma unroll
    for (int mA = 0; mA < 2; ++mA)
      ah[mA] = *(const f16x8*)(xh0 + mA * 16384 + k0);
#pragma unroll
    for (int nB = 0; nB < 4; ++nB) {
      bh[nB] = *(const f16x8*)(wh0 + nB * 16384 + k0);
      bl[nB] = *(const f16x8*)(wl0 + nB * 16384 + k0);
    }
#pragma unroll
    for (int mA = 0; mA < 2; ++mA)
#pragma unroll
      for (int nB = 0; nB < 4; ++nB) {
        aM[mA][nB] = __builtin_amdgcn_mfma_f32_16x16x32_f16(ah[mA], bh[nB], aM[mA][nB], 0, 0, 0);
        aC[mA][nB] = __builtin_amdgcn_mfma_f32_16x16x32_f16(ah[mA], bl[nB], aC[mA][nB], 0, 0, 0);
      }
  }

  const float eps = 4.8828125e-4f;  // 2^-11
  const float unscale = 0x1p-80f;
  float bb[4];
#pragma unroll
  for (int nB = 0; nB < 4; ++nB) bb[nB] = bias[n0 + nB * 16 + l15];
#pragma unroll
  for (int mA = 0; mA < 2; ++mA)
#pragma unroll
    for (int nB = 0; nB < 4; ++nB) {
      const int n = n0 + nB * 16 + l15;
#pragma unroll
      for (int r = 0; r < 4; ++r) {
        const int m = m0 + mA * 16 + lhi * 4 + r;
        out[(size_t)m * 1024 + n] =
            (aM[mA][nB][r] + aC[mA][nB][r] * eps) * unscale + bb[nB];
      }
    }
}

// ---------------------------------------------------------------------------
extern "C" void kernel_launch(void* const* d_in, const int* in_sizes, int n_in,
                              void* d_out, int out_size, void* d_ws,
                              size_t ws_size, hipStream_t stream) {
  (void)in_sizes; (void)n_in; (void)out_size; (void)ws_size;
  const float* hs    = (const float*)d_in[0];
  const float* amask = (const float*)d_in[1];
  const float* Wq    = (const float*)d_in[2];
  const float* bq    = (const float*)d_in[3];
  // d_in[4], d_in[5] = Wk, bk : projected-but-unused in the reference
  const float* Wv    = (const float*)d_in[6];
  const float* bv    = (const float*)d_in[7];
  const float* Wo    = (const float*)d_in[8];
  const float* bo    = (const float*)d_in[9];
  const float* mu    = (const float*)d_in[10];
  const float* prec  = (const float*)d_in[11];
  const float* spw   = (const float*)d_in[12];
  float* out = (float*)d_out;

  // Peak = 15,728,640 floats (proven budget). Float-offset lifetimes:
  //  [0,4194304)        Xh/Xl -> R/tneg/lswg (prep..phi3) -> per-half P
  //                     planes P0/P1 [0,3670016) -> Wot (gemmo)
  //  [4194304,8388608)  Qh/Ql (..phi3) -> V [5505024,7602176)
  //                     + af [7602176,7667712) + Wvth [7667712,8192000)
  //  [8388608,15728640) Wqt (..gemmq) -> Lt (phi3..psi1) ; ctx fp16
  //                     [8388608,10485760) in dead Lt-lo after psi0;
  //                     Lt-hi [12058624,15728640) live until psi1.
  float* w = (float*)d_ws;
  _Float16* Xh   = (_Float16*)w;
  _Float16* Xl   = (_Float16*)(w + 2097152);
  _Float16* Rh   = (_Float16*)w;
  _Float16* Rl   = (_Float16*)(w + 229376);
  float*    tneg = w + 458752;
  float*    lswg = w + 465920;
  unsigned short* P0 = (unsigned short*)w;          // [0, 1835008)
  unsigned short* P1 = (unsigned short*)(w + 1835008);
  _Float16* Qh   = (_Float16*)(w + 4194304);
  _Float16* Ql   = (_Float16*)(w + 6291456);
  float*    V    = w + 5505024;                     // [5505024, 7602176)
  float*    af   = w + 7602176;                     // [7602176, 7667712)
  _Float16* Wvth = (_Float16*)(w + 7667712);        // [7667712, 8192000)
  _Float16* Wqth = (_Float16*)(w + 8388608);
  _Float16* Wqtl = (_Float16*)(w + 8912896);
  float*    Lt   = w + 8388608;                     // [8388608, 15728640)
  _Float16* ctxh = (_Float16*)(w + 8388608);        // [8388608, 10485760)
  _Float16* Woth = (_Float16*)w;                    // [0, 524288)
  _Float16* Wotl = (_Float16*)(w + 524288);         // [524288, 1048576)

  split_x<<<dim3(2048), dim3(256), 0, stream>>>(hs, Xh, Xl);
  transpose_split<<<dim3(16, 16), dim3(256), 0, stream>>>(Wq, Wqth, Wqtl);
  gemmq_mfma<<<dim3(16, 32), dim3(256), 0, stream>>>(Xh, Xl, Wqth, Wqtl, bq, Qh, Ql);
  prep_kernel<<<dim3(NP), dim3(256), 0, stream>>>(mu, prec, spw, Rh, Rl, tneg, lswg);
  phi3<<<dim3(256, 8), dim3(256), 0, stream>>>(Qh, Ql, Rh, Rl, tneg, lswg, Lt);
  transpose_h<<<dim3(16, 16), dim3(256), 0, stream>>>(Wv, Wvth);
  for (int half = 0; half < 2; ++half) {
    const int bh0 = half * 32;
    psi_kernel<<<dim3(512), dim3(256), 0, stream>>>(Lt, P0, P1, af, bh0);
    gemmv_mfma<<<dim3(16, 16), dim3(256), 0, stream>>>(hs, Wvth, bv, V,
                                                       half * 2048, bh0);
    attn6_kernel<<<dim3(2048), dim3(512), 0, stream>>>(P0, P1, af, V, amask,
                                                       ctxh, bh0);
  }
  transpose_split<<<dim3(16, 16), dim3(256), 0, stream>>>(Wo, Woth, Wotl);
  gemmo_mfma<<<dim3(16, 32), dim3(256), 0, stream>>>(ctxh, Woth, Wotl, bo, out);
}

// Round 18
// 648.726 us; speedup vs baseline: 1.0034x; 1.0034x over previous
//
#include <hip/hip_runtime.h>
#include <cstdint>
#include <cstddef>

// Problem constants (fixed by the reference)
#define NB 4
#define NS 1024
#define ND 1024
#define NH 16
#define NDH 64
#define NP 112
#define NTOPK 64
#define NZCAP 128   // per-row compacted nonzero capacity
#define PCH 14      // splats per phi chunk (8 chunks)

typedef _Float16 f16x8 __attribute__((ext_vector_type(8)));
typedef short bf16x8 __attribute__((ext_vector_type(8)));
typedef float f32x4 __attribute__((ext_vector_type(4)));
typedef unsigned short u16x8 __attribute__((ext_vector_type(8)));

// RNE float -> bf16 bits
__device__ __forceinline__ unsigned short bf16r(float f) {
  const unsigned u = __float_as_uint(f);
  return (unsigned short)((u + 0x7FFFu + ((u >> 16) & 1u)) >> 16);
}

// ---------------------------------------------------------------------------
// prep v4: fp64 Cholesky, transposed LDS layout A2[e][t] = A[t][e], trailing
// update parallelized across 4 waves (j strided by q). Bitwise-identical
// fp64 ops in identical k-order. (validated round 16)
// ---------------------------------------------------------------------------
__global__ __launch_bounds__(256) void prep_kernel(
    const float* __restrict__ mu, const float* __restrict__ prec,
    const float* __restrict__ spw, _Float16* __restrict__ Rh,
    _Float16* __restrict__ Rl, float* __restrict__ tneg,
    float* __restrict__ lswg) {
  __shared__ double A2[64][64];  // 32 KB, A2[e][t] = A[t][e]
  const int p = blockIdx.x;
  const int t = threadIdx.x & 63, q = threadIdx.x >> 6;

  for (int e = q; e < 64; e += 4)
    A2[e][t] = (double)prec[((size_t)p * 64 + e) * 64 + t];  // symmetric read
  __syncthreads();

  for (int k = 0; k < 64; ++k) {
    if (threadIdx.x == k) A2[k][k] = sqrt(A2[k][k]);
    __syncthreads();
    if (q == 0 && t > k) A2[k][t] /= A2[k][k];
    __syncthreads();
    const double lik = A2[k][t];  // meaningful only for t > k (loop guards)
    for (int j = k + 1 + q; j <= t; j += 4)
      A2[j][t] -= lik * A2[k][j];  // distinct (j,t) per thread; reads row k
    __syncthreads();
  }

  for (int d = q; d < 64; d += 4) {
    const float rv = (t >= d) ? (float)A2[d][t] : 0.f;
    const _Float16 h = (_Float16)rv;
    Rh[((size_t)p << 12) + (d << 6) + t] = h;
    Rl[((size_t)p << 12) + (d << 6) + t] =
        (_Float16)((rv - (float)h) * 2048.0f);
  }

  if (q == 0) {
    double s = 0.0;
    for (int e = t; e < 64; ++e) s += A2[t][e] * (double)mu[p * 64 + e];
    tneg[p * 64 + t] = (float)(-s);
  }
  if (threadIdx.x == 0) lswg[p] = 0.5f * logf(spw[p]);
}

// ---------------------------------------------------------------------------
// split_x: fp32 -> fp16 hi + (lo * 2048), elementwise (8 elems/thread)
// ---------------------------------------------------------------------------
__global__ __launch_bounds__(256) void split_x(
    const float* __restrict__ X, _Float16* __restrict__ Xh,
    _Float16* __restrict__ Xl) {
  const size_t i = ((size_t)blockIdx.x * 256 + threadIdx.x) * 8;
  const float4 a = *(const float4*)(X + i);
  const float4 b = *(const float4*)(X + i + 4);
  const float v[8] = {a.x, a.y, a.z, a.w, b.x, b.y, b.z, b.w};
  f16x8 hv, lv;
#pragma unroll
  for (int j = 0; j < 8; ++j) {
    const _Float16 h = (_Float16)v[j];
    hv[j] = h;
    lv[j] = (_Float16)((v[j] - (float)h) * 2048.0f);
  }
  *(f16x8*)(Xh + i) = hv;
  *(f16x8*)(Xl + i) = lv;
}

// ---------------------------------------------------------------------------
// transpose_split: W[k][n] fp32 (1024x1024) -> Th/Tl [n][k] fp16 split
// ---------------------------------------------------------------------------
__global__ __launch_bounds__(256) void transpose_split(
    const float* __restrict__ W, _Float16* __restrict__ Th,
    _Float16* __restrict__ Tl) {
  __shared__ float T[64][65];
  const int tid = threadIdx.x;
  const int k0 = blockIdx.x * 64, n0 = blockIdx.y * 64;
  const int c = tid & 63, rb = tid >> 6;
#pragma unroll 4
  for (int i = 0; i < 16; ++i) {
    const int r = rb * 16 + i;
    T[r][c] = W[(size_t)(k0 + r) * 1024 + n0 + c];
  }
  __syncthreads();
#pragma unroll 4
  for (int i = 0; i < 16; ++i) {
    const int r = rb * 16 + i;               // local n
    const float v = T[c][r];                 // = W[k0+c][n0+r]
    const _Float16 h = (_Float16)v;
    Th[(size_t)(n0 + r) * 1024 + k0 + c] = h;
    Tl[(size_t)(n0 + r) * 1024 + k0 + c] = (_Float16)((v - (float)h) * 2048.0f);
  }
}

// ---------------------------------------------------------------------------
// transpose_h: W[k][n] fp32 -> Th [n][k] fp16 (hi plane only)
// ---------------------------------------------------------------------------
__global__ __launch_bounds__(256) void transpose_h(
    const float* __restrict__ W, _Float16* __restrict__ Th) {
  __shared__ float T[64][65];
  const int tid = threadIdx.x;
  const int k0 = blockIdx.x * 64, n0 = blockIdx.y * 64;
  const int c = tid & 63, rb = tid >> 6;
#pragma unroll 4
  for (int i = 0; i < 16; ++i) {
    const int r = rb * 16 + i;
    T[r][c] = W[(size_t)(k0 + r) * 1024 + n0 + c];
  }
  __syncthreads();
#pragma unroll 4
  for (int i = 0; i < 16; ++i) {
    const int r = rb * 16 + i;
    Th[(size_t)(n0 + r) * 1024 + k0 + c] = (_Float16)T[c][r];
  }
}

// ---------------------------------------------------------------------------
// gemmq_mfma: Q = (hs @ Wq + bq) * 0.125 via fp16-split MFMA (hh + hl + lh),
// output fp16-split Qh/Ql in [bh][s][d] layout. (validated round 6)
// ---------------------------------------------------------------------------
__global__ __launch_bounds__(256, 2) void gemmq_mfma(
    const _Float16* __restrict__ Xh, const _Float16* __restrict__ Xl,
    const _Float16* __restrict__ Wth, const _Float16* __restrict__ Wtl,
    const float* __restrict__ bias, _Float16* __restrict__ QhO,
    _Float16* __restrict__ QlO) {
  const int tid = threadIdx.x, lane = tid & 63, wv = tid >> 6;
  const int l15 = lane & 15, lhi = lane >> 4;
  const int n0 = blockIdx.x * 64;
  const int m0 = blockIdx.y * 128 + wv * 32;

  f32x4 aM[2][4], aC[2][4];
#pragma unroll
  for (int i = 0; i < 2; ++i)
#pragma unroll
    for (int j = 0; j < 4; ++j) {
      const f32x4 z = {0.f, 0.f, 0.f, 0.f};
      aM[i][j] = z; aC[i][j] = z;
    }

  const _Float16* xh0 = Xh + (size_t)(m0 + l15) * 1024 + lhi * 8;
  const _Float16* xl0 = Xl + (size_t)(m0 + l15) * 1024 + lhi * 8;
  const _Float16* wh0 = Wth + (size_t)(n0 + l15) * 1024 + lhi * 8;
  const _Float16* wl0 = Wtl + (size_t)(n0 + l15) * 1024 + lhi * 8;

#pragma unroll 4
  for (int k0 = 0; k0 < 1024; k0 += 32) {
    f16x8 ah[2], al[2], bh[4], bl[4];
#pragma unroll
    for (int mA = 0; mA < 2; ++mA) {
      ah[mA] = *(const f16x8*)(xh0 + mA * 16384 + k0);
      al[mA] = *(const f16x8*)(xl0 + mA * 16384 + k0);
    }
#pragma unroll
    for (int nB = 0; nB < 4; ++nB) {
      bh[nB] = *(const f16x8*)(wh0 + nB * 16384 + k0);
      bl[nB] = *(const f16x8*)(wl0 + nB * 16384 + k0);
    }
#pragma unroll
    for (int mA = 0; mA < 2; ++mA)
#pragma unroll
      for (int nB = 0; nB < 4; ++nB) {
        aM[mA][nB] = __builtin_amdgcn_mfma_f32_16x16x32_f16(ah[mA], bh[nB], aM[mA][nB], 0, 0, 0);
        aC[mA][nB] = __builtin_amdgcn_mfma_f32_16x16x32_f16(ah[mA], bl[nB], aC[mA][nB], 0, 0, 0);
        aC[mA][nB] = __builtin_amdgcn_mfma_f32_16x16x32_f16(al[mA], bh[nB], aC[mA][nB], 0, 0, 0);
      }
  }

  const float eps = 4.8828125e-4f;  // 2^-11
  const int h = n0 >> 6;
  float bq[4];
#pragma unroll
  for (int nB = 0; nB < 4; ++nB) bq[nB] = bias[n0 + nB * 16 + l15];
#pragma unroll
  for (int mA = 0; mA < 2; ++mA)
#pragma unroll
    for (int nB = 0; nB < 4; ++nB) {
      const int dd = nB * 16 + l15;
#pragma unroll
      for (int r = 0; r < 4; ++r) {
        const int m = m0 + mA * 16 + lhi * 4 + r;
        const int b = m >> 10, s = m & 1023;
        const float v = (aM[mA][nB][r] + aC[mA][nB][r] * eps + bq[nB]) * 0.125f;
        const _Float16 hh = (_Float16)v;
        const size_t o = ((((size_t)b * NH + h) << 10) + s) * 64 + dd;
        QhO[o] = hh;
        QlO[o] = (_Float16)((v - (float)hh) * 2048.0f);
      }
    }
}

// ---------------------------------------------------------------------------
// gemmv_mfma: V-half = hs @ Wv + bv via fp16 MFMA (A converted in-register
// RNE, B single fp16 plane). fp32 output, head-split [lbh][s][64].
// ---------------------------------------------------------------------------
__global__ __launch_bounds__(256, 2) void gemmv_mfma(
    const float* __restrict__ X, const _Float16* __restrict__ Wth,
    const float* __restrict__ bias, float* __restrict__ dst,
    int moff, int bh0) {
  const int tid = threadIdx.x, lane = tid & 63, wv = tid >> 6;
  const int l15 = lane & 15, lhi = lane >> 4;
  const int n0 = blockIdx.x * 64;
  const int m0 = moff + blockIdx.y * 128 + wv * 32;

  f32x4 acc[2][4];
#pragma unroll
  for (int i = 0; i < 2; ++i)
#pragma unroll
    for (int j = 0; j < 4; ++j) {
      const f32x4 z = {0.f, 0.f, 0.f, 0.f};
      acc[i][j] = z;
    }

  const float* x0 = X + (size_t)(m0 + l15) * 1024 + lhi * 8;
  const _Float16* w0 = Wth + (size_t)(n0 + l15) * 1024 + lhi * 8;

#pragma unroll 4
  for (int k0 = 0; k0 < 1024; k0 += 32) {
    f16x8 ah[2], bh[4];
#pragma unroll
    for (int mA = 0; mA < 2; ++mA) {
      const float4 a = *(const float4*)(x0 + mA * 16384 + k0);
      const float4 b = *(const float4*)(x0 + mA * 16384 + k0 + 4);
      f16x8 hv;
      hv[0] = (_Float16)a.x; hv[1] = (_Float16)a.y;
      hv[2] = (_Float16)a.z; hv[3] = (_Float16)a.w;
      hv[4] = (_Float16)b.x; hv[5] = (_Float16)b.y;
      hv[6] = (_Float16)b.z; hv[7] = (_Float16)b.w;
      ah[mA] = hv;
    }
#pragma unroll
    for (int nB = 0; nB < 4; ++nB)
      bh[nB] = *(const f16x8*)(w0 + nB * 16384 + k0);
#pragma unroll
    for (int mA = 0; mA < 2; ++mA)
#pragma unroll
      for (int nB = 0; nB < 4; ++nB)
        acc[mA][nB] = __builtin_amdgcn_mfma_f32_16x16x32_f16(
            ah[mA], bh[nB], acc[mA][nB], 0, 0, 0);
  }

  const int h = n0 >> 6;
  float bb[4];
#pragma unroll
  for (int nB = 0; nB < 4; ++nB) bb[nB] = bias[n0 + nB * 16 + l15];
#pragma unroll
  for (int mA = 0; mA < 2; ++mA)
#pragma unroll
    for (int nB = 0; nB < 4; ++nB) {
      const int dd = nB * 16 + l15;
#pragma unroll
      for (int r = 0; r < 4; ++r) {
        const int m = m0 + mA * 16 + lhi * 4 + r;
        const int bidx = m >> 10, s = m & 1023;
        const int lbh = (bidx << 4) + h - bh0;
        dst[((((size_t)lbh << 10) + s) << 6) + dd] = acc[mA][nB][r] + bb[nB];
      }
    }
}

// ---------------------------------------------------------------------------
// phi v3 (log-domain): ls = 0.5*log(w) - 0.5*||R q + tneg||^2 via MFMA,
// R double-buffered in LDS (XOR-swizzle both sides). Writes Lt[bh][p][s].
// ---------------------------------------------------------------------------
__global__ __launch_bounds__(256, 2) void phi3(
    const _Float16* __restrict__ Qh, const _Float16* __restrict__ Ql,
    const _Float16* __restrict__ Rh, const _Float16* __restrict__ Rl,
    const float* __restrict__ tneg, const float* __restrict__ lswg,
    float* __restrict__ Lt) {
  __shared__ __align__(16) _Float16 RhS[2][4096];
  __shared__ __align__(16) _Float16 RlS[2][4096];
  __shared__ __align__(16) float tns[PCH * 64];
  __shared__ float lsws[PCH];
  const int tid = threadIdx.x, lane = tid & 63, wv = tid >> 6;
  const int l15 = lane & 15, lhi = lane >> 4;
  const int tokbase = blockIdx.x * 256;
  const int tb = tokbase + wv * 64;
  const int pbase = blockIdx.y * PCH;
  const float eps = 4.8828125e-4f;

  for (int i = tid; i < PCH * 16; i += 256)
    ((float4*)tns)[i] = ((const float4*)(tneg + (pbase << 6)))[i];
  if (tid < PCH) lsws[tid] = lswg[pbase + tid];

  f16x8 qb[4][2][2];
#pragma unroll
  for (int T = 0; T < 4; ++T)
#pragma unroll
    for (int c = 0; c < 2; ++c) {
      const size_t off = ((size_t)(tb + T * 16 + l15) << 6) + c * 32 + lhi * 8;
      qb[T][c][0] = *(const f16x8*)(Qh + off);
      qb[T][c][1] = *(const f16x8*)(Ql + off);
    }

  f16x8 sgH[2], sgL[2];
#define PHI_LOAD(p)                                                          \
  {                                                                          \
    const _Float16* rhp = Rh + ((size_t)(pbase + (p)) << 12);                \
    const _Float16* rlp = Rl + ((size_t)(pbase + (p)) << 12);                \
    _Pragma("unroll") for (int j = 0; j < 2; ++j) {                          \
      const int X = tid * 32 + j * 16;                                       \
      const int src = X ^ (((X >> 7) & 7) << 4);                             \
      sgH[j] = *(const f16x8*)((const char*)rhp + src);                      \
      sgL[j] = *(const f16x8*)((const char*)rlp + src);                      \
    }                                                                        \
  }
#define PHI_WRITE(buf)                                                       \
  {                                                                          \
    _Pragma("unroll") for (int j = 0; j < 2; ++j) {                          \
      const int X = tid * 32 + j * 16;                                       \
      *(f16x8*)((char*)&RhS[buf][0] + X) = sgH[j];                           \
      *(f16x8*)((char*)&RlS[buf][0] + X) = sgL[j];                           \
    }                                                                        \
  }

  PHI_LOAD(0)
  PHI_WRITE(0)

  float* ub = Lt + (((size_t)(tokbase >> 10) * NP) << 10);
  const int sbase = (tb & 1023);

  for (int pi = 0; pi < PCH; ++pi) {
    __syncthreads();
    const int buf = pi & 1;
    if (pi + 1 < PCH) PHI_LOAD(pi + 1)

    float sq0 = 0.f, sq1 = 0.f, sq2 = 0.f, sq3 = 0.f;
#pragma unroll
    for (int mt = 0; mt < 4; ++mt) {
      const float4 tv = *(const float4*)&tns[(pi << 6) + mt * 16 + lhi * 4];
      const f32x4 ti = {tv.x, tv.y, tv.z, tv.w};
      const f32x4 z = {0.f, 0.f, 0.f, 0.f};
      f32x4 aM[4], aC[4];
#pragma unroll
      for (int T = 0; T < 4; ++T) { aM[T] = ti; aC[T] = z; }
#pragma unroll
      for (int c = 0; c < 2; ++c) {
        if (mt >= 2 && c == 0) continue;  // upper-tri zero block
        const int row = mt * 16 + l15;
        int bo = row * 128 + c * 64 + lhi * 16;
        bo ^= ((row & 7) << 4);
        const f16x8 ah = *(const f16x8*)((const char*)&RhS[buf][0] + bo);
        const f16x8 al = *(const f16x8*)((const char*)&RlS[buf][0] + bo);
#pragma unroll
        for (int T = 0; T < 4; ++T) {
          aM[T] = __builtin_amdgcn_mfma_f32_16x16x32_f16(ah, qb[T][c][0], aM[T], 0, 0, 0);
          aC[T] = __builtin_amdgcn_mfma_f32_16x16x32_f16(ah, qb[T][c][1], aC[T], 0, 0, 0);
          aC[T] = __builtin_amdgcn_mfma_f32_16x16x32_f16(al, qb[T][c][0], aC[T], 0, 0, 0);
        }
      }
#pragma unroll
      for (int r = 0; r < 4; ++r) {
        float y;
        y = aM[0][r] + aC[0][r] * eps; sq0 += y * y;
        y = aM[1][r] + aC[1][r] * eps; sq1 += y * y;
        y = aM[2][r] + aC[2][r] * eps; sq2 += y * y;
        y = aM[3][r] + aC[3][r] * eps; sq3 += y * y;
      }
    }
    sq0 += __shfl_xor(sq0, 16, 64); sq0 += __shfl_xor(sq0, 32, 64);
    sq1 += __shfl_xor(sq1, 16, 64); sq1 += __shfl_xor(sq1, 32, 64);
    sq2 += __shfl_xor(sq2, 16, 64); sq2 += __shfl_xor(sq2, 32, 64);
    sq3 += __shfl_xor(sq3, 16, 64); sq3 += __shfl_xor(sq3, 32, 64);
    const float sqs = (lhi == 0) ? sq0 : (lhi == 1) ? sq1 : (lhi == 2) ? sq2 : sq3;
    ub[((size_t)(pbase + pi) << 10) + sbase + lane] = lsws[pi] - 0.5f * sqs;

    __syncthreads();
    if (pi + 1 < PCH) PHI_WRITE(buf ^ 1)
  }
#undef PHI_LOAD
#undef PHI_WRITE
}

// ---------------------------------------------------------------------------
// psi v3: 64 tokens x 4 splat-groups per block (512 blocks/half). ls held in
// 28 registers, one expf pass, TWO exact bf16 planes. LDS-staged coalesced
// u16x8 write-out to token-major [lbh][s][112].
// ---------------------------------------------------------------------------
__global__ __launch_bounds__(256) void psi_kernel(
    const float* __restrict__ Lt, unsigned short* __restrict__ P0,
    unsigned short* __restrict__ P1, float* __restrict__ af, int bh0) {
  __shared__ unsigned short Ls[2][64 * 120];  // 30 KB
  __shared__ float pmax[4][64];
  const int tid = threadIdx.x;
  const int lbh = blockIdx.x >> 4;
  const int gbh = bh0 + lbh;
  const int s0 = (blockIdx.x & 15) << 6;
  const int tok = tid & 63, pg = tid >> 6;

  const float* col = Lt + ((size_t)gbh * NP + pg * 28) * 1024 + s0 + tok;
  float ls[28];
  float a = -3.4e38f;
#pragma unroll
  for (int j = 0; j < 28; ++j) {
    ls[j] = col[(size_t)j << 10];
    a = fmaxf(a, ls[j]);
  }
  pmax[pg][tok] = a;
  __syncthreads();
  a = fmaxf(fmaxf(pmax[0][tok], pmax[1][tok]),
            fmaxf(pmax[2][tok], pmax[3][tok]));
  if (pg == 0) af[(gbh << 10) + s0 + tok] = a;

  const int rbase = tok * 120 + pg * 28;
#pragma unroll
  for (int jj = 0; jj < 14; ++jj) {
    unsigned short v0[2], v1[2];
#pragma unroll
    for (int e = 0; e < 2; ++e) {
      const float x = expf(ls[jj * 2 + e] - a);
      const unsigned short b0 = bf16r(x);
      const float f0 = __uint_as_float((unsigned)b0 << 16);
      const unsigned short b1 = bf16r((x - f0) * 256.0f);  // exact residual
      if (e == 0) { v0[0] = b0; v0[1] = b1; }
      else        { v1[0] = b0; v1[1] = b1; }
    }
#pragma unroll
    for (int pl = 0; pl < 2; ++pl) {
      ushort2 pk; pk.x = v0[pl]; pk.y = v1[pl];
      *(ushort2*)&Ls[pl][rbase + jj * 2] = pk;
    }
  }
  __syncthreads();

  // coalesced write-out: 896 u16x8 per plane
  const size_t gb = (size_t)((lbh << 10) + s0) * NP;
#pragma unroll 1
  for (int pl = 0; pl < 2; ++pl) {
    unsigned short* dst = (pl == 0 ? P0 : P1) + gb;
    const unsigned short* src = &Ls[pl][0];
    for (int i = tid; i < 896; i += 256) {
      const int t2 = i / 14;
      const int off = (i - t2 * 14) * 8;
      *(u16x8*)(dst + t2 * 112 + off) = *(const u16x8*)(src + t2 * 120 + off);
    }
  }
}

// G-tile fp16 LDS addressing: in-row XOR swizzle spreads the 4 lhi write
// groups across distinct bank octets; read side uses the same row-uniform XOR.
#define GADDR(row, col) \
  (((row) << 11) + ((((col) << 1) ^ ((((row) >> 2) & 3) << 5))))

// ---------------------------------------------------------------------------
// attn7: TILE=32 rows/block (1024 blocks/half) -- halves per-row staging
// (eajs/msks/expf), A-fragment loads, and launch tails vs TILE=16. G tile
// fp16 via GADDR swizzle: 32 rows x 2KB = 64 KB + 8 KB aux = 72 KB (the
// round-11/16-proven footprint). Waves 0-3 own row-tile 0, waves 4-7 row-
// tile 1; each wave sweeps 16 j-tiles (pipelined B loads). Per-row math
// value-identical: bf16x2 Gram, exact top-64 bit-search from MSB(row max),
// rowsum->inv, compact into dead G rows, 8-wide sparse V gather, ctx fp16
// pre-scaled 2^80. XCD grid: bhl = ((id>>8)<<3)|(id&7), tile = (id>>3)&31.
// ---------------------------------------------------------------------------
__global__ __launch_bounds__(512) void attn7_kernel(
    const unsigned short* __restrict__ P0, const unsigned short* __restrict__ P1,
    const float* __restrict__ af, const float* __restrict__ V,
    const float* __restrict__ amask, _Float16* __restrict__ ctxh, int bh0) {
  __shared__ __align__(16) _Float16 Ath[32 * 1024];  // 64 KB: G tile fp16
  __shared__ __align__(16) float eajs[1024];         // 4 KB: exp(a_j)
  __shared__ __align__(16) float msks[1024];         // 4 KB: mask row
  const int tid = threadIdx.x;
  const int id = blockIdx.x;
  const int bhl = ((id >> 8) << 3) | (id & 7);   // 0..31 local
  const int gbh = bh0 + bhl;
  const int i0 = ((id >> 3) & 31) * 32;
  const int bidx = gbh >> 4;
  const int h = gbh & 15;
  const int lane = tid & 63, wv = tid >> 6;
  const int l15 = lane & 15, lhi = lane >> 4;
  const float* afb = af + (gbh << 10);
  char* Ab = (char*)Ath;

  eajs[tid] = expf(afb[tid]);
  eajs[tid + 512] = expf(afb[tid + 512]);
  msks[tid] = amask[(bidx << 10) + tid];
  msks[tid + 512] = amask[(bidx << 10) + tid + 512];

  // ---- Gram via bf16x2 MFMA: waves 0-3 -> rows i0..i0+15, 4-7 -> +16 ----
  {
    const unsigned short* Pb0 = P0 + (size_t)(bhl << 10) * NP;
    const unsigned short* Pb1 = P1 + (size_t)(bhl << 10) * NP;
    const bf16x8 zz = {0, 0, 0, 0, 0, 0, 0, 0};
    const int rt = wv >> 2;          // row-tile 0/1
    const int jw = wv & 3;           // j-tile group: 16 tiles each
    bf16x8 A0[4], A1[4];
    {
      const size_t ro = (size_t)(i0 + rt * 16 + l15) * NP;
#pragma unroll
      for (int c = 0; c < 3; ++c) {
        A0[c] = *(const bf16x8*)(Pb0 + ro + c * 32 + lhi * 8);
        A1[c] = *(const bf16x8*)(Pb1 + ro + c * 32 + lhi * 8);
      }
      A0[3] = (lhi < 2) ? *(const bf16x8*)(Pb0 + ro + 96 + lhi * 8) : zz;
      A1[3] = (lhi < 2) ? *(const bf16x8*)(Pb1 + ro + 96 + lhi * 8) : zz;
    }

#define LOADB(dst, Pb, jtv)                                                  \
  {                                                                          \
    const size_t co = (size_t)((jtv) * 16 + l15) * NP;                       \
    _Pragma("unroll") for (int c = 0; c < 3; ++c)                            \
        dst[c] = *(const bf16x8*)(Pb + co + c * 32 + lhi * 8);               \
    dst[3] = (lhi < 2) ? *(const bf16x8*)(Pb + co + 96 + lhi * 8) : zz;      \
  }

    bf16x8 B0c[4], B1c[4], B0n[4];
    LOADB(B0c, Pb0, jw * 16)
    LOADB(B1c, Pb1, jw * 16)

#pragma unroll 1
    for (int jt16 = 0; jt16 < 16; ++jt16) {
      const int jt = jw * 16 + jt16;
      if (jt16 < 15) LOADB(B0n, Pb0, jt + 1)  // prefetch next hi plane
      f32x4 g0 = {0.f, 0.f, 0.f, 0.f};
      f32x4 g1a = {0.f, 0.f, 0.f, 0.f}, g1b = {0.f, 0.f, 0.f, 0.f};
      __builtin_amdgcn_s_setprio(1);
#pragma unroll
      for (int c = 0; c < 4; ++c) {
        g0  = __builtin_amdgcn_mfma_f32_16x16x32_bf16(A0[c], B0c[c], g0, 0, 0, 0);
        g1a = __builtin_amdgcn_mfma_f32_16x16x32_bf16(A0[c], B1c[c], g1a, 0, 0, 0);
        g1b = __builtin_amdgcn_mfma_f32_16x16x32_bf16(A1[c], B0c[c], g1b, 0, 0, 0);
      }
      __builtin_amdgcn_s_setprio(0);
#pragma unroll
      for (int r = 0; r < 4; ++r) {
        const float g = fmaxf(g0[r] + (g1a[r] + g1b[r]) * 0.00390625f, 0.f);
        *(_Float16*)(Ab + GADDR(rt * 16 + lhi * 4 + r, jt * 16 + l15)) =
            (_Float16)g;
      }
      if (jt16 < 15) {
        LOADB(B1c, Pb1, jt + 1)  // lo plane: hides under next g0 chain
#pragma unroll
        for (int c = 0; c < 4; ++c) B0c[c] = B0n[c];
      }
    }
#undef LOADB
  }
  __syncthreads();

  // ---- per-wave: 4 rows: fv, exact top-64 thr, rowsum->inv, compact, ctx --
  {
    const float* Vb = V + ((size_t)bhl << 16);
    int cnts[4];

#pragma unroll
    for (int rr = 0; rr < 4; ++rr) {
      const int r = wv * 4 + rr;
      const float eai = expf(afb[i0 + r]);
      float fv[16], fm[16];
      float mx = 0.f;
#pragma unroll
      for (int k = 0; k < 16; ++k) {
        const int j = k * 64 + lane;
        const float gv = (float)*(const _Float16*)(Ab + GADDR(r, j));
        fv[k] = eai * (eajs[j] * gv);
        fm[k] = fv[k] * msks[j];
        mx = fmaxf(mx, fv[k]);
      }
      // wave max -> start bit (skipped candidates all have cnt==0)
#pragma unroll
      for (int off = 32; off > 0; off >>= 1) mx = fmaxf(mx, __shfl_xor(mx, off, 64));
      const unsigned mu = __float_as_uint(mx);
      const int startbit = (mu == 0u) ? 0 : (31 - __clz(mu));
      unsigned c = 0u;
      for (int bit = startbit; bit >= 0; --bit) {
        const unsigned cand = c | (1u << bit);
        int cnt = 0;
#pragma unroll
        for (int k = 0; k < 16; ++k)
          cnt += (int)__popcll(__ballot(__float_as_uint(fv[k]) >= cand));
        if (cnt >= NTOPK) {
          c = cand;
          if (cnt == NTOPK) break;
        }
      }
      const float thr = __uint_as_float(c);
      float ssum = 0.f;
#pragma unroll
      for (int k = 0; k < 16; ++k) ssum += (fv[k] >= thr) ? fm[k] : 0.f;
#pragma unroll
      for (int off = 32; off > 0; off >>= 1) ssum += __shfl_xor(ssum, off, 64);
      const float inv = 1.0f / fmaxf(ssum, 1e-12f);

      // compact into this row's (now dead) G storage: raw addressing
      float* nzv = (float*)(Ab + (r << 11));
      int* nzi = (int*)(Ab + (r << 11) + 512);
      unsigned cnt = 0;
#pragma unroll
      for (int k = 0; k < 16; ++k) {
        const bool keep = (fv[k] >= thr) && (fm[k] > 0.f);
        const unsigned long long b = __ballot(keep);
        if (keep) {
          const unsigned pos = cnt + (unsigned)__popcll(b & ((1ull << lane) - 1ull));
          if (pos < NZCAP) {
            nzi[pos] = k * 64 + lane;
            nzv[pos] = fm[k] * inv;
          }
        }
        cnt += (unsigned)__popcll(b);
      }
      cnts[rr] = (int)(cnt < NZCAP ? cnt : NZCAP);
    }

#pragma unroll
    for (int rr = 0; rr < 4; ++rr) {
      const int r = wv * 4 + rr;
      const float* nzv = (const float*)(Ab + (r << 11));
      const int* nzi = (const int*)(Ab + (r << 11) + 512);
      const int n = cnts[rr];
      float a0 = 0.f, a1 = 0.f, a2 = 0.f, a3 = 0.f;
      int t = 0;
      for (; t + 8 <= n; t += 8) {
        const int j0 = nzi[t], j1 = nzi[t + 1], j2 = nzi[t + 2], j3 = nzi[t + 3];
        const int j4 = nzi[t + 4], j5 = nzi[t + 5], j6 = nzi[t + 6], j7 = nzi[t + 7];
        const float w0 = nzv[t], w1 = nzv[t + 1], w2 = nzv[t + 2], w3 = nzv[t + 3];
        const float w4 = nzv[t + 4], w5 = nzv[t + 5], w6 = nzv[t + 6], w7 = nzv[t + 7];
        const float v0 = Vb[(j0 << 6) + lane];
        const float v1 = Vb[(j1 << 6) + lane];
        const float v2 = Vb[(j2 << 6) + lane];
        const float v3 = Vb[(j3 << 6) + lane];
        const float v4 = Vb[(j4 << 6) + lane];
        const float v5 = Vb[(j5 << 6) + lane];
        const float v6 = Vb[(j6 << 6) + lane];
        const float v7 = Vb[(j7 << 6) + lane];
        a0 += w0 * v0; a1 += w1 * v1; a2 += w2 * v2; a3 += w3 * v3;
        a0 += w4 * v4; a1 += w5 * v5; a2 += w6 * v6; a3 += w7 * v7;
      }
      for (; t < n; ++t) a0 += nzv[t] * Vb[(nzi[t] << 6) + lane];
      const float s = ((a0 + a1) + (a2 + a3)) * 0x1p80f;  // pre-scale 2^80
      ctxh[(size_t)((bidx << 10) + i0 + r) * 1024 + (h << 6) + lane] =
          (_Float16)s;
    }
  }
}

// ---------------------------------------------------------------------------
// gemmo_mfma: out = ctx_f16 @ Wo_split * 2^-80 + bo. A = single fp16 plane.
// ---------------------------------------------------------------------------
__global__ __launch_bounds__(256, 2) void gemmo_mfma(
    const _Float16* __restrict__ Ch, const _Float16* __restrict__ Wth,
    const _Float16* __restrict__ Wtl, const float* __restrict__ bias,
    float* __restrict__ out) {
  const int tid = threadIdx.x, lane = tid & 63, wv = tid >> 6;
  const int l15 = lane & 15, lhi = lane >> 4;
  const int n0 = blockIdx.x * 64;
  const int m0 = blockIdx.y * 128 + wv * 32;

  f32x4 aM[2][4], aC[2][4];
#pragma unroll
  for (int i = 0; i < 2; ++i)
#pragma unroll
    for (int j = 0; j < 4; ++j) {
      const f32x4 z = {0.f, 0.f, 0.f, 0.f};
      aM[i][j] = z; aC[i][j] = z;
    }

  const _Float16* xh0 = Ch + (size_t)(m0 + l15) * 1024 + lhi * 8;
  const _Float16* wh0 = Wth + (size_t)(n0 + l15) * 1024 + lhi * 8;
  const _Float16* wl0 = Wtl + (size_t)(n0 + l15) * 1024 + lhi * 8;

#pragma unroll 4
  for (int k0 = 0; k0 < 1024; k0 += 32) {
    f16x8 ah[2], bh[4], bl[4];
#pragma unroll
    for (int mA = 0; mA < 2; ++mA)
      ah[mA] = *(const f16x8*)(xh0 + mA * 16384 + k0);
#pragma unroll
    for (int nB = 0; nB < 4; ++nB) {
      bh[nB] = *(const f16x8*)(wh0 + nB * 16384 + k0);
      bl[nB] = *(const f16x8*)(wl0 + nB * 16384 + k0);
    }
#pragma unroll
    for (int mA = 0; mA < 2; ++mA)
#pragma unroll
      for (int nB = 0; nB < 4; ++nB) {
        aM[mA][nB] = __builtin_amdgcn_mfma_f32_16x16x32_f16(ah[mA], bh[nB], aM[mA][nB], 0, 0, 0);
        aC[mA][nB] = __builtin_amdgcn_mfma_f32_16x16x32_f16(ah[mA], bl[nB], aC[mA][nB], 0, 0, 0);
      }
  }

  const float eps = 4.8828125e-4f;  // 2^-11
  const float unscale = 0x1p-80f;
  float bb[4];
#pragma unroll
  for (int nB = 0; nB < 4; ++nB) bb[nB] = bias[n0 + nB * 16 + l15];
#pragma unroll
  for (int mA = 0; mA < 2; ++mA)
#pragma unroll
    for (int nB = 0; nB < 4; ++nB) {
      const int n = n0 + nB * 16 + l15;
#pragma unroll
      for (int r = 0; r < 4; ++r) {
        const int m = m0 + mA * 16 + lhi * 4 + r;
        out[(size_t)m * 1024 + n] =
            (aM[mA][nB][r] + aC[mA][nB][r] * eps) * unscale + bb[nB];
      }
    }
}

// ---------------------------------------------------------------------------
extern "C" void kernel_launch(void* const* d_in, const int* in_sizes, int n_in,
                              void* d_out, int out_size, void* d_ws,
                              size_t ws_size, hipStream_t stream) {
  (void)in_sizes; (void)n_in; (void)out_size; (void)ws_size;
  const float* hs    = (const float*)d_in[0];
  const float* amask = (const float*)d_in[1];
  const float* Wq    = (const float*)d_in[2];
  const float* bq    = (const float*)d_in[3];
  // d_in[4], d_in[5] = Wk, bk : projected-but-unused in the reference
  const float* Wv    = (const float*)d_in[6];
  const float* bv    = (const float*)d_in[7];
  const float* Wo    = (const float*)d_in[8];
  const float* bo    = (const float*)d_in[9];
  const float* mu    = (const float*)d_in[10];
  const float* prec  = (const float*)d_in[11];
  const float* spw   = (const float*)d_in[12];
  float* out = (float*)d_out;

  // Peak = 15,728,640 floats (proven budget). Float-offset lifetimes:
  //  [0,4194304)        Xh/Xl -> R/tneg/lswg (prep..phi3) -> per-half P
  //                     planes P0/P1 [0,3670016) -> Wot (gemmo)
  //  [4194304,8388608)  Qh/Ql (..phi3) -> V [5505024,7602176)
  //                     + af [7602176,7667712) + Wvth [7667712,8192000)
  //  [8388608,15728640) Wqt (..gemmq) -> Lt (phi3..psi1) ; ctx fp16
  //                     [8388608,10485760) in dead Lt-lo after psi0;
  //                     Lt-hi [12058624,15728640) live until psi1.
  float* w = (float*)d_ws;
  _Float16* Xh   = (_Float16*)w;
  _Float16* Xl   = (_Float16*)(w + 2097152);
  _Float16* Rh   = (_Float16*)w;
  _Float16* Rl   = (_Float16*)(w + 229376);
  float*    tneg = w + 458752;
  float*    lswg = w + 465920;
  unsigned short* P0 = (unsigned short*)w;          // [0, 1835008)
  unsigned short* P1 = (unsigned short*)(w + 1835008);
  _Float16* Qh   = (_Float16*)(w + 4194304);
  _Float16* Ql   = (_Float16*)(w + 6291456);
  float*    V    = w + 5505024;                     // [5505024, 7602176)
  float*    af   = w + 7602176;                     // [7602176, 7667712)
  _Float16* Wvth = (_Float16*)(w + 7667712);        // [7667712, 8192000)
  _Float16* Wqth = (_Float16*)(w + 8388608);
  _Float16* Wqtl = (_Float16*)(w + 8912896);
  float*    Lt   = w + 8388608;                     // [8388608, 15728640)
  _Float16* ctxh = (_Float16*)(w + 8388608);        // [8388608, 10485760)
  _Float16* Woth = (_Float16*)w;                    // [0, 524288)
  _Float16* Wotl = (_Float16*)(w + 524288);         // [524288, 1048576)

  split_x<<<dim3(2048), dim3(256), 0, stream>>>(hs, Xh, Xl);
  transpose_split<<<dim3(16, 16), dim3(256), 0, stream>>>(Wq, Wqth, Wqtl);
  gemmq_mfma<<<dim3(16, 32), dim3(256), 0, stream>>>(Xh, Xl, Wqth, Wqtl, bq, Qh, Ql);
  prep_kernel<<<dim3(NP), dim3(256), 0, stream>>>(mu, prec, spw, Rh, Rl, tneg, lswg);
  phi3<<<dim3(256, 8), dim3(256), 0, stream>>>(Qh, Ql, Rh, Rl, tneg, lswg, Lt);
  transpose_h<<<dim3(16, 16), dim3(256), 0, stream>>>(Wv, Wvth);
  for (int half = 0; half < 2; ++half) {
    const int bh0 = half * 32;
    psi_kernel<<<dim3(512), dim3(256), 0, stream>>>(Lt, P0, P1, af, bh0);
    gemmv_mfma<<<dim3(16, 16), dim3(256), 0, stream>>>(hs, Wvth, bv, V,
                                                       half * 2048, bh0);
    attn7_kernel<<<dim3(1024), dim3(512), 0, stream>>>(P0, P1, af, V, amask,
                                                       ctxh, bh0);
  }
  transpose_split<<<dim3(16, 16), dim3(256), 0, stream>>>(Wo, Woth, Wotl);
  gemmo_mfma<<<dim3(16, 32), dim3(256), 0, stream>>>(ctxh, Woth, Wotl, bo, out);
}

// Round 19
// 594.820 us; speedup vs baseline: 1.0943x; 1.0906x over previous
//
#include <hip/hip_runtime.h>
#include <cstdint>
#include <cstddef>

// Problem constants (fixed by the reference)
#define NB 4
#define NS 1024
#define ND 1024
#define NH 16
#define NDH 64
#define NP 112
#define NTOPK 64
#define NZCAP 128   // per-row compacted nonzero capacity
#define PCH 14      // splats per phi chunk (8 chunks)

typedef _Float16 f16x8 __attribute__((ext_vector_type(8)));
typedef short bf16x8 __attribute__((ext_vector_type(8)));
typedef float f32x4 __attribute__((ext_vector_type(4)));
typedef unsigned short u16x8 __attribute__((ext_vector_type(8)));

// RNE float -> bf16 bits
__device__ __forceinline__ unsigned short bf16r(float f) {
  const unsigned u = __float_as_uint(f);
  return (unsigned short)((u + 0x7FFFu + ((u >> 16) & 1u)) >> 16);
}

// ---------------------------------------------------------------------------
// prep v4: fp64 Cholesky, transposed LDS layout A2[e][t] = A[t][e], trailing
// update parallelized across 4 waves. Bitwise-identical fp64 ops. (r16)
// ---------------------------------------------------------------------------
__global__ __launch_bounds__(256) void prep_kernel(
    const float* __restrict__ mu, const float* __restrict__ prec,
    const float* __restrict__ spw, _Float16* __restrict__ Rh,
    _Float16* __restrict__ Rl, float* __restrict__ tneg,
    float* __restrict__ lswg) {
  __shared__ double A2[64][64];  // 32 KB, A2[e][t] = A[t][e]
  const int p = blockIdx.x;
  const int t = threadIdx.x & 63, q = threadIdx.x >> 6;

  for (int e = q; e < 64; e += 4)
    A2[e][t] = (double)prec[((size_t)p * 64 + e) * 64 + t];  // symmetric read
  __syncthreads();

  for (int k = 0; k < 64; ++k) {
    if (threadIdx.x == k) A2[k][k] = sqrt(A2[k][k]);
    __syncthreads();
    if (q == 0 && t > k) A2[k][t] /= A2[k][k];
    __syncthreads();
    const double lik = A2[k][t];  // meaningful only for t > k (loop guards)
    for (int j = k + 1 + q; j <= t; j += 4)
      A2[j][t] -= lik * A2[k][j];  // distinct (j,t) per thread; reads row k
    __syncthreads();
  }

  for (int d = q; d < 64; d += 4) {
    const float rv = (t >= d) ? (float)A2[d][t] : 0.f;
    const _Float16 h = (_Float16)rv;
    Rh[((size_t)p << 12) + (d << 6) + t] = h;
    Rl[((size_t)p << 12) + (d << 6) + t] =
        (_Float16)((rv - (float)h) * 2048.0f);
  }

  if (q == 0) {
    double s = 0.0;
    for (int e = t; e < 64; ++e) s += A2[t][e] * (double)mu[p * 64 + e];
    tneg[p * 64 + t] = (float)(-s);
  }
  if (threadIdx.x == 0) lswg[p] = 0.5f * logf(spw[p]);
}

// ---------------------------------------------------------------------------
// split_x: fp32 -> fp16 hi + (lo * 2048), elementwise (8 elems/thread)
// ---------------------------------------------------------------------------
__global__ __launch_bounds__(256) void split_x(
    const float* __restrict__ X, _Float16* __restrict__ Xh,
    _Float16* __restrict__ Xl) {
  const size_t i = ((size_t)blockIdx.x * 256 + threadIdx.x) * 8;
  const float4 a = *(const float4*)(X + i);
  const float4 b = *(const float4*)(X + i + 4);
  const float v[8] = {a.x, a.y, a.z, a.w, b.x, b.y, b.z, b.w};
  f16x8 hv, lv;
#pragma unroll
  for (int j = 0; j < 8; ++j) {
    const _Float16 h = (_Float16)v[j];
    hv[j] = h;
    lv[j] = (_Float16)((v[j] - (float)h) * 2048.0f);
  }
  *(f16x8*)(Xh + i) = hv;
  *(f16x8*)(Xl + i) = lv;
}

// ---------------------------------------------------------------------------
// transpose_split: W[k][n] fp32 (1024x1024) -> Th/Tl [n][k] fp16 split
// ---------------------------------------------------------------------------
__global__ __launch_bounds__(256) void transpose_split(
    const float* __restrict__ W, _Float16* __restrict__ Th,
    _Float16* __restrict__ Tl) {
  __shared__ float T[64][65];
  const int tid = threadIdx.x;
  const int k0 = blockIdx.x * 64, n0 = blockIdx.y * 64;
  const int c = tid & 63, rb = tid >> 6;
#pragma unroll 4
  for (int i = 0; i < 16; ++i) {
    const int r = rb * 16 + i;
    T[r][c] = W[(size_t)(k0 + r) * 1024 + n0 + c];
  }
  __syncthreads();
#pragma unroll 4
  for (int i = 0; i < 16; ++i) {
    const int r = rb * 16 + i;               // local n
    const float v = T[c][r];                 // = W[k0+c][n0+r]
    const _Float16 h = (_Float16)v;
    Th[(size_t)(n0 + r) * 1024 + k0 + c] = h;
    Tl[(size_t)(n0 + r) * 1024 + k0 + c] = (_Float16)((v - (float)h) * 2048.0f);
  }
}

// ---------------------------------------------------------------------------
// transpose_h: W[k][n] fp32 -> Th [n][k] fp16 (hi plane only)
// ---------------------------------------------------------------------------
__global__ __launch_bounds__(256) void transpose_h(
    const float* __restrict__ W, _Float16* __restrict__ Th) {
  __shared__ float T[64][65];
  const int tid = threadIdx.x;
  const int k0 = blockIdx.x * 64, n0 = blockIdx.y * 64;
  const int c = tid & 63, rb = tid >> 6;
#pragma unroll 4
  for (int i = 0; i < 16; ++i) {
    const int r = rb * 16 + i;
    T[r][c] = W[(size_t)(k0 + r) * 1024 + n0 + c];
  }
  __syncthreads();
#pragma unroll 4
  for (int i = 0; i < 16; ++i) {
    const int r = rb * 16 + i;
    Th[(size_t)(n0 + r) * 1024 + k0 + c] = (_Float16)T[c][r];
  }
}

// ---------------------------------------------------------------------------
// gemmq_mfma: Q = (hs @ Wq + bq) * 0.125 via fp16-split MFMA (hh + hl + lh),
// output fp16-split Qh/Ql in [bh][s][d] layout. (validated round 6)
// ---------------------------------------------------------------------------
__global__ __launch_bounds__(256, 2) void gemmq_mfma(
    const _Float16* __restrict__ Xh, const _Float16* __restrict__ Xl,
    const _Float16* __restrict__ Wth, const _Float16* __restrict__ Wtl,
    const float* __restrict__ bias, _Float16* __restrict__ QhO,
    _Float16* __restrict__ QlO) {
  const int tid = threadIdx.x, lane = tid & 63, wv = tid >> 6;
  const int l15 = lane & 15, lhi = lane >> 4;
  const int n0 = blockIdx.x * 64;
  const int m0 = blockIdx.y * 128 + wv * 32;

  f32x4 aM[2][4], aC[2][4];
#pragma unroll
  for (int i = 0; i < 2; ++i)
#pragma unroll
    for (int j = 0; j < 4; ++j) {
      const f32x4 z = {0.f, 0.f, 0.f, 0.f};
      aM[i][j] = z; aC[i][j] = z;
    }

  const _Float16* xh0 = Xh + (size_t)(m0 + l15) * 1024 + lhi * 8;
  const _Float16* xl0 = Xl + (size_t)(m0 + l15) * 1024 + lhi * 8;
  const _Float16* wh0 = Wth + (size_t)(n0 + l15) * 1024 + lhi * 8;
  const _Float16* wl0 = Wtl + (size_t)(n0 + l15) * 1024 + lhi * 8;

#pragma unroll 4
  for (int k0 = 0; k0 < 1024; k0 += 32) {
    f16x8 ah[2], al[2], bh[4], bl[4];
#pragma unroll
    for (int mA = 0; mA < 2; ++mA) {
      ah[mA] = *(const f16x8*)(xh0 + mA * 16384 + k0);
      al[mA] = *(const f16x8*)(xl0 + mA * 16384 + k0);
    }
#pragma unroll
    for (int nB = 0; nB < 4; ++nB) {
      bh[nB] = *(const f16x8*)(wh0 + nB * 16384 + k0);
      bl[nB] = *(const f16x8*)(wl0 + nB * 16384 + k0);
    }
#pragma unroll
    for (int mA = 0; mA < 2; ++mA)
#pragma unroll
      for (int nB = 0; nB < 4; ++nB) {
        aM[mA][nB] = __builtin_amdgcn_mfma_f32_16x16x32_f16(ah[mA], bh[nB], aM[mA][nB], 0, 0, 0);
        aC[mA][nB] = __builtin_amdgcn_mfma_f32_16x16x32_f16(ah[mA], bl[nB], aC[mA][nB], 0, 0, 0);
        aC[mA][nB] = __builtin_amdgcn_mfma_f32_16x16x32_f16(al[mA], bh[nB], aC[mA][nB], 0, 0, 0);
      }
  }

  const float eps = 4.8828125e-4f;  // 2^-11
  const int h = n0 >> 6;
  float bq[4];
#pragma unroll
  for (int nB = 0; nB < 4; ++nB) bq[nB] = bias[n0 + nB * 16 + l15];
#pragma unroll
  for (int mA = 0; mA < 2; ++mA)
#pragma unroll
    for (int nB = 0; nB < 4; ++nB) {
      const int dd = nB * 16 + l15;
#pragma unroll
      for (int r = 0; r < 4; ++r) {
        const int m = m0 + mA * 16 + lhi * 4 + r;
        const int b = m >> 10, s = m & 1023;
        const float v = (aM[mA][nB][r] + aC[mA][nB][r] * eps + bq[nB]) * 0.125f;
        const _Float16 hh = (_Float16)v;
        const size_t o = ((((size_t)b * NH + h) << 10) + s) * 64 + dd;
        QhO[o] = hh;
        QlO[o] = (_Float16)((v - (float)hh) * 2048.0f);
      }
    }
}

// ---------------------------------------------------------------------------
// gemmv_mfma: V = hs @ Wv + bv via fp16 MFMA (A converted in-register RNE,
// B single fp16 plane). fp32 output, head-split [bh][s][64]. Full pass.
// ---------------------------------------------------------------------------
__global__ __launch_bounds__(256, 2) void gemmv_mfma(
    const float* __restrict__ X, const _Float16* __restrict__ Wth,
    const float* __restrict__ bias, float* __restrict__ dst) {
  const int tid = threadIdx.x, lane = tid & 63, wv = tid >> 6;
  const int l15 = lane & 15, lhi = lane >> 4;
  const int n0 = blockIdx.x * 64;
  const int m0 = blockIdx.y * 128 + wv * 32;

  f32x4 acc[2][4];
#pragma unroll
  for (int i = 0; i < 2; ++i)
#pragma unroll
    for (int j = 0; j < 4; ++j) {
      const f32x4 z = {0.f, 0.f, 0.f, 0.f};
      acc[i][j] = z;
    }

  const float* x0 = X + (size_t)(m0 + l15) * 1024 + lhi * 8;
  const _Float16* w0 = Wth + (size_t)(n0 + l15) * 1024 + lhi * 8;

#pragma unroll 4
  for (int k0 = 0; k0 < 1024; k0 += 32) {
    f16x8 ah[2], bh[4];
#pragma unroll
    for (int mA = 0; mA < 2; ++mA) {
      const float4 a = *(const float4*)(x0 + mA * 16384 + k0);
      const float4 b = *(const float4*)(x0 + mA * 16384 + k0 + 4);
      f16x8 hv;
      hv[0] = (_Float16)a.x; hv[1] = (_Float16)a.y;
      hv[2] = (_Float16)a.z; hv[3] = (_Float16)a.w;
      hv[4] = (_Float16)b.x; hv[5] = (_Float16)b.y;
      hv[6] = (_Float16)b.z; hv[7] = (_Float16)b.w;
      ah[mA] = hv;
    }
#pragma unroll
    for (int nB = 0; nB < 4; ++nB)
      bh[nB] = *(const f16x8*)(w0 + nB * 16384 + k0);
#pragma unroll
    for (int mA = 0; mA < 2; ++mA)
#pragma unroll
      for (int nB = 0; nB < 4; ++nB)
        acc[mA][nB] = __builtin_amdgcn_mfma_f32_16x16x32_f16(
            ah[mA], bh[nB], acc[mA][nB], 0, 0, 0);
  }

  const int h = n0 >> 6;
  float bb[4];
#pragma unroll
  for (int nB = 0; nB < 4; ++nB) bb[nB] = bias[n0 + nB * 16 + l15];
#pragma unroll
  for (int mA = 0; mA < 2; ++mA)
#pragma unroll
    for (int nB = 0; nB < 4; ++nB) {
      const int dd = nB * 16 + l15;
#pragma unroll
      for (int r = 0; r < 4; ++r) {
        const int m = m0 + mA * 16 + lhi * 4 + r;
        const int bidx = m >> 10, s = m & 1023;
        const int bh_ = (bidx << 4) + h;
        dst[((((size_t)bh_ << 10) + s) << 6) + dd] = acc[mA][nB][r] + bb[nB];
      }
    }
}

// ---------------------------------------------------------------------------
// phi v3 (log-domain): ls = 0.5*log(w) - 0.5*||R q + tneg||^2 via MFMA,
// R double-buffered in LDS (XOR-swizzle both sides). Writes Lt[bh][p][s].
// ---------------------------------------------------------------------------
__global__ __launch_bounds__(256, 2) void phi3(
    const _Float16* __restrict__ Qh, const _Float16* __restrict__ Ql,
    const _Float16* __restrict__ Rh, const _Float16* __restrict__ Rl,
    const float* __restrict__ tneg, const float* __restrict__ lswg,
    float* __restrict__ Lt) {
  __shared__ __align__(16) _Float16 RhS[2][4096];
  __shared__ __align__(16) _Float16 RlS[2][4096];
  __shared__ __align__(16) float tns[PCH * 64];
  __shared__ float lsws[PCH];
  const int tid = threadIdx.x, lane = tid & 63, wv = tid >> 6;
  const int l15 = lane & 15, lhi = lane >> 4;
  const int tokbase = blockIdx.x * 256;
  const int tb = tokbase + wv * 64;
  const int pbase = blockIdx.y * PCH;
  const float eps = 4.8828125e-4f;

  for (int i = tid; i < PCH * 16; i += 256)
    ((float4*)tns)[i] = ((const float4*)(tneg + (pbase << 6)))[i];
  if (tid < PCH) lsws[tid] = lswg[pbase + tid];

  f16x8 qb[4][2][2];
#pragma unroll
  for (int T = 0; T < 4; ++T)
#pragma unroll
    for (int c = 0; c < 2; ++c) {
      const size_t off = ((size_t)(tb + T * 16 + l15) << 6) + c * 32 + lhi * 8;
      qb[T][c][0] = *(const f16x8*)(Qh + off);
      qb[T][c][1] = *(const f16x8*)(Ql + off);
    }

  f16x8 sgH[2], sgL[2];
#define PHI_LOAD(p)                                                          \
  {                                                                          \
    const _Float16* rhp = Rh + ((size_t)(pbase + (p)) << 12);                \
    const _Float16* rlp = Rl + ((size_t)(pbase + (p)) << 12);                \
    _Pragma("unroll") for (int j = 0; j < 2; ++j) {                          \
      const int X = tid * 32 + j * 16;                                       \
      const int src = X ^ (((X >> 7) & 7) << 4);                             \
      sgH[j] = *(const f16x8*)((const char*)rhp + src);                      \
      sgL[j] = *(const f16x8*)((const char*)rlp + src);                      \
    }                                                                        \
  }
#define PHI_WRITE(buf)                                                       \
  {                                                                          \
    _Pragma("unroll") for (int j = 0; j < 2; ++j) {                          \
      const int X = tid * 32 + j * 16;                                       \
      *(f16x8*)((char*)&RhS[buf][0] + X) = sgH[j];                           \
      *(f16x8*)((char*)&RlS[buf][0] + X) = sgL[j];                           \
    }                                                                        \
  }

  PHI_LOAD(0)
  PHI_WRITE(0)

  float* ub = Lt + (((size_t)(tokbase >> 10) * NP) << 10);
  const int sbase = (tb & 1023);

  for (int pi = 0; pi < PCH; ++pi) {
    __syncthreads();
    const int buf = pi & 1;
    if (pi + 1 < PCH) PHI_LOAD(pi + 1)

    float sq0 = 0.f, sq1 = 0.f, sq2 = 0.f, sq3 = 0.f;
#pragma unroll
    for (int mt = 0; mt < 4; ++mt) {
      const float4 tv = *(const float4*)&tns[(pi << 6) + mt * 16 + lhi * 4];
      const f32x4 ti = {tv.x, tv.y, tv.z, tv.w};
      const f32x4 z = {0.f, 0.f, 0.f, 0.f};
      f32x4 aM[4], aC[4];
#pragma unroll
      for (int T = 0; T < 4; ++T) { aM[T] = ti; aC[T] = z; }
#pragma unroll
      for (int c = 0; c < 2; ++c) {
        if (mt >= 2 && c == 0) continue;  // upper-tri zero block
        const int row = mt * 16 + l15;
        int bo = row * 128 + c * 64 + lhi * 16;
        bo ^= ((row & 7) << 4);
        const f16x8 ah = *(const f16x8*)((const char*)&RhS[buf][0] + bo);
        const f16x8 al = *(const f16x8*)((const char*)&RlS[buf][0] + bo);
#pragma unroll
        for (int T = 0; T < 4; ++T) {
          aM[T] = __builtin_amdgcn_mfma_f32_16x16x32_f16(ah, qb[T][c][0], aM[T], 0, 0, 0);
          aC[T] = __builtin_amdgcn_mfma_f32_16x16x32_f16(ah, qb[T][c][1], aC[T], 0, 0, 0);
          aC[T] = __builtin_amdgcn_mfma_f32_16x16x32_f16(al, qb[T][c][0], aC[T], 0, 0, 0);
        }
      }
#pragma unroll
      for (int r = 0; r < 4; ++r) {
        float y;
        y = aM[0][r] + aC[0][r] * eps; sq0 += y * y;
        y = aM[1][r] + aC[1][r] * eps; sq1 += y * y;
        y = aM[2][r] + aC[2][r] * eps; sq2 += y * y;
        y = aM[3][r] + aC[3][r] * eps; sq3 += y * y;
      }
    }
    sq0 += __shfl_xor(sq0, 16, 64); sq0 += __shfl_xor(sq0, 32, 64);
    sq1 += __shfl_xor(sq1, 16, 64); sq1 += __shfl_xor(sq1, 32, 64);
    sq2 += __shfl_xor(sq2, 16, 64); sq2 += __shfl_xor(sq2, 32, 64);
    sq3 += __shfl_xor(sq3, 16, 64); sq3 += __shfl_xor(sq3, 32, 64);
    const float sqs = (lhi == 0) ? sq0 : (lhi == 1) ? sq1 : (lhi == 2) ? sq2 : sq3;
    ub[((size_t)(pbase + pi) << 10) + sbase + lane] = lsws[pi] - 0.5f * sqs;

    __syncthreads();
    if (pi + 1 < PCH) PHI_WRITE(buf ^ 1)
  }
#undef PHI_LOAD
#undef PHI_WRITE
}

// ---------------------------------------------------------------------------
// psi v4: FULL pass (1024 blocks, 64 bh). 64 tokens x 4 splat-groups per
// block; ls in 28 registers, one expf pass, TWO exact bf16 planes.
// LDS-staged coalesced u16x8 write-out to token-major [bh][s][112].
// ---------------------------------------------------------------------------
__global__ __launch_bounds__(256) void psi_kernel(
    const float* __restrict__ Lt, unsigned short* __restrict__ P0,
    unsigned short* __restrict__ P1, float* __restrict__ af) {
  __shared__ unsigned short Ls[2][64 * 120];  // 30 KB
  __shared__ float pmax[4][64];
  const int tid = threadIdx.x;
  const int gbh = blockIdx.x >> 4;
  const int s0 = (blockIdx.x & 15) << 6;
  const int tok = tid & 63, pg = tid >> 6;

  const float* col = Lt + ((size_t)gbh * NP + pg * 28) * 1024 + s0 + tok;
  float ls[28];
  float a = -3.4e38f;
#pragma unroll
  for (int j = 0; j < 28; ++j) {
    ls[j] = col[(size_t)j << 10];
    a = fmaxf(a, ls[j]);
  }
  pmax[pg][tok] = a;
  __syncthreads();
  a = fmaxf(fmaxf(pmax[0][tok], pmax[1][tok]),
            fmaxf(pmax[2][tok], pmax[3][tok]));
  if (pg == 0) af[(gbh << 10) + s0 + tok] = a;

  const int rbase = tok * 120 + pg * 28;
#pragma unroll
  for (int jj = 0; jj < 14; ++jj) {
    unsigned short v0[2], v1[2];
#pragma unroll
    for (int e = 0; e < 2; ++e) {
      const float x = expf(ls[jj * 2 + e] - a);
      const unsigned short b0 = bf16r(x);
      const float f0 = __uint_as_float((unsigned)b0 << 16);
      const unsigned short b1 = bf16r((x - f0) * 256.0f);  // exact residual
      if (e == 0) { v0[0] = b0; v0[1] = b1; }
      else        { v1[0] = b0; v1[1] = b1; }
    }
#pragma unroll
    for (int pl = 0; pl < 2; ++pl) {
      ushort2 pk; pk.x = v0[pl]; pk.y = v1[pl];
      *(ushort2*)&Ls[pl][rbase + jj * 2] = pk;
    }
  }
  __syncthreads();

  // coalesced write-out: 896 u16x8 per plane
  const size_t gb = (size_t)((gbh << 10) + s0) * NP;
#pragma unroll 1
  for (int pl = 0; pl < 2; ++pl) {
    unsigned short* dst = (pl == 0 ? P0 : P1) + gb;
    const unsigned short* src = &Ls[pl][0];
    for (int i = tid; i < 896; i += 256) {
      const int t2 = i / 14;
      const int off = (i - t2 * 14) * 8;
      *(u16x8*)(dst + t2 * 112 + off) = *(const u16x8*)(src + t2 * 120 + off);
    }
  }
}

// G-tile fp16 LDS addressing: in-row XOR swizzle spreads the 4 lhi write
// groups across distinct bank octets; read side uses the same row-uniform XOR.
#define GADDR(row, col) \
  (((row) << 11) + ((((col) << 1) ^ ((((row) >> 2) & 3) << 5))))

// ---------------------------------------------------------------------------
// attn8: FULL pass, 2048 blocks, TILE=32 rows/block. G tile fp16 via GADDR
// swizzle (64 KB + 8 KB aux). Waves 0-3 row-tile 0, 4-7 row-tile 1; each
// wave 16 j-tiles (pipelined B loads). Per-row math value-identical: bf16x2
// Gram, exact top-64 bit-search from MSB(row max), rowsum->inv, compact into
// dead G rows, 16-wide sparse V gather, ctx fp16 pre-scaled 2^80.
// XCD grid: bh = ((id>>8)<<3)|(id&7) in 0..63, tile = (id>>3)&31.
// ---------------------------------------------------------------------------
__global__ __launch_bounds__(512) void attn8_kernel(
    const unsigned short* __restrict__ P0, const unsigned short* __restrict__ P1,
    const float* __restrict__ af, const float* __restrict__ V,
    const float* __restrict__ amask, _Float16* __restrict__ ctxh) {
  __shared__ __align__(16) _Float16 Ath[32 * 1024];  // 64 KB: G tile fp16
  __shared__ __align__(16) float eajs[1024];         // 4 KB: exp(a_j)
  __shared__ __align__(16) float msks[1024];         // 4 KB: mask row
  const int tid = threadIdx.x;
  const int id = blockIdx.x;
  const int gbh = ((id >> 8) << 3) | (id & 7);   // 0..63
  const int i0 = ((id >> 3) & 31) * 32;
  const int bidx = gbh >> 4;
  const int h = gbh & 15;
  const int lane = tid & 63, wv = tid >> 6;
  const int l15 = lane & 15, lhi = lane >> 4;
  const float* afb = af + (gbh << 10);
  char* Ab = (char*)Ath;

  eajs[tid] = expf(afb[tid]);
  eajs[tid + 512] = expf(afb[tid + 512]);
  msks[tid] = amask[(bidx << 10) + tid];
  msks[tid + 512] = amask[(bidx << 10) + tid + 512];

  // ---- Gram via bf16x2 MFMA: waves 0-3 -> rows i0..i0+15, 4-7 -> +16 ----
  {
    const unsigned short* Pb0 = P0 + (size_t)(gbh << 10) * NP;
    const unsigned short* Pb1 = P1 + (size_t)(gbh << 10) * NP;
    const bf16x8 zz = {0, 0, 0, 0, 0, 0, 0, 0};
    const int rt = wv >> 2;          // row-tile 0/1
    const int jw = wv & 3;           // j-tile group: 16 tiles each
    bf16x8 A0[4], A1[4];
    {
      const size_t ro = (size_t)(i0 + rt * 16 + l15) * NP;
#pragma unroll
      for (int c = 0; c < 3; ++c) {
        A0[c] = *(const bf16x8*)(Pb0 + ro + c * 32 + lhi * 8);
        A1[c] = *(const bf16x8*)(Pb1 + ro + c * 32 + lhi * 8);
      }
      A0[3] = (lhi < 2) ? *(const bf16x8*)(Pb0 + ro + 96 + lhi * 8) : zz;
      A1[3] = (lhi < 2) ? *(const bf16x8*)(Pb1 + ro + 96 + lhi * 8) : zz;
    }

#define LOADB(dst, Pb, jtv)                                                  \
  {                                                                          \
    const size_t co = (size_t)((jtv) * 16 + l15) * NP;                       \
    _Pragma("unroll") for (int c = 0; c < 3; ++c)                            \
        dst[c] = *(const bf16x8*)(Pb + co + c * 32 + lhi * 8);               \
    dst[3] = (lhi < 2) ? *(const bf16x8*)(Pb + co + 96 + lhi * 8) : zz;      \
  }

    bf16x8 B0c[4], B1c[4], B0n[4];
    LOADB(B0c, Pb0, jw * 16)
    LOADB(B1c, Pb1, jw * 16)

#pragma unroll 1
    for (int jt16 = 0; jt16 < 16; ++jt16) {
      const int jt = jw * 16 + jt16;
      if (jt16 < 15) LOADB(B0n, Pb0, jt + 1)  // prefetch next hi plane
      f32x4 g0 = {0.f, 0.f, 0.f, 0.f};
      f32x4 g1a = {0.f, 0.f, 0.f, 0.f}, g1b = {0.f, 0.f, 0.f, 0.f};
      __builtin_amdgcn_s_setprio(1);
#pragma unroll
      for (int c = 0; c < 4; ++c) {
        g0  = __builtin_amdgcn_mfma_f32_16x16x32_bf16(A0[c], B0c[c], g0, 0, 0, 0);
        g1a = __builtin_amdgcn_mfma_f32_16x16x32_bf16(A0[c], B1c[c], g1a, 0, 0, 0);
        g1b = __builtin_amdgcn_mfma_f32_16x16x32_bf16(A1[c], B0c[c], g1b, 0, 0, 0);
      }
      __builtin_amdgcn_s_setprio(0);
#pragma unroll
      for (int r = 0; r < 4; ++r) {
        const float g = fmaxf(g0[r] + (g1a[r] + g1b[r]) * 0.00390625f, 0.f);
        *(_Float16*)(Ab + GADDR(rt * 16 + lhi * 4 + r, jt * 16 + l15)) =
            (_Float16)g;
      }
      if (jt16 < 15) {
        LOADB(B1c, Pb1, jt + 1)  // lo plane: hides under next g0 chain
#pragma unroll
        for (int c = 0; c < 4; ++c) B0c[c] = B0n[c];
      }
    }
#undef LOADB
  }
  __syncthreads();

  // ---- per-wave: 4 rows: fv, exact top-64 thr, rowsum->inv, compact, ctx --
  {
    const float* Vb = V + ((size_t)gbh << 16);
    int cnts[4];

#pragma unroll
    for (int rr = 0; rr < 4; ++rr) {
      const int r = wv * 4 + rr;
      const float eai = expf(afb[i0 + r]);
      float fv[16], fm[16];
      float mx = 0.f;
#pragma unroll
      for (int k = 0; k < 16; ++k) {
        const int j = k * 64 + lane;
        const float gv = (float)*(const _Float16*)(Ab + GADDR(r, j));
        fv[k] = eai * (eajs[j] * gv);
        fm[k] = fv[k] * msks[j];
        mx = fmaxf(mx, fv[k]);
      }
      // wave max -> start bit (skipped candidates all have cnt==0)
#pragma unroll
      for (int off = 32; off > 0; off >>= 1) mx = fmaxf(mx, __shfl_xor(mx, off, 64));
      const unsigned mu = __float_as_uint(mx);
      const int startbit = (mu == 0u) ? 0 : (31 - __clz(mu));
      unsigned c = 0u;
      for (int bit = startbit; bit >= 0; --bit) {
        const unsigned cand = c | (1u << bit);
        int cnt = 0;
#pragma unroll
        for (int k = 0; k < 16; ++k)
          cnt += (int)__popcll(__ballot(__float_as_uint(fv[k]) >= cand));
        if (cnt >= NTOPK) {
          c = cand;
          if (cnt == NTOPK) break;
        }
      }
      const float thr = __uint_as_float(c);
      float ssum = 0.f;
#pragma unroll
      for (int k = 0; k < 16; ++k) ssum += (fv[k] >= thr) ? fm[k] : 0.f;
#pragma unroll
      for (int off = 32; off > 0; off >>= 1) ssum += __shfl_xor(ssum, off, 64);
      const float inv = 1.0f / fmaxf(ssum, 1e-12f);

      // compact into this row's (now dead) G storage: raw addressing
      float* nzv = (float*)(Ab + (r << 11));
      int* nzi = (int*)(Ab + (r << 11) + 512);
      unsigned cnt = 0;
#pragma unroll
      for (int k = 0; k < 16; ++k) {
        const bool keep = (fv[k] >= thr) && (fm[k] > 0.f);
        const unsigned long long b = __ballot(keep);
        if (keep) {
          const unsigned pos = cnt + (unsigned)__popcll(b & ((1ull << lane) - 1ull));
          if (pos < NZCAP) {
            nzi[pos] = k * 64 + lane;
            nzv[pos] = fm[k] * inv;
          }
        }
        cnt += (unsigned)__popcll(b);
      }
      cnts[rr] = (int)(cnt < NZCAP ? cnt : NZCAP);
    }

#pragma unroll
    for (int rr = 0; rr < 4; ++rr) {
      const int r = wv * 4 + rr;
      const float* nzv = (const float*)(Ab + (r << 11));
      const int* nzi = (const int*)(Ab + (r << 11) + 512);
      const int n = cnts[rr];
      float a0 = 0.f, a1 = 0.f, a2 = 0.f, a3 = 0.f;
      int t = 0;
      for (; t + 16 <= n; t += 16) {
        int jj[16]; float ww[16], vv[16];
#pragma unroll
        for (int u = 0; u < 16; ++u) { jj[u] = nzi[t + u]; ww[u] = nzv[t + u]; }
#pragma unroll
        for (int u = 0; u < 16; ++u) vv[u] = Vb[(jj[u] << 6) + lane];
#pragma unroll
        for (int u = 0; u < 16; ++u) {
          if ((u & 3) == 0) a0 += ww[u] * vv[u];
          else if ((u & 3) == 1) a1 += ww[u] * vv[u];
          else if ((u & 3) == 2) a2 += ww[u] * vv[u];
          else a3 += ww[u] * vv[u];
        }
      }
      for (; t + 8 <= n; t += 8) {
        int jj[8]; float ww[8], vv[8];
#pragma unroll
        for (int u = 0; u < 8; ++u) { jj[u] = nzi[t + u]; ww[u] = nzv[t + u]; }
#pragma unroll
        for (int u = 0; u < 8; ++u) vv[u] = Vb[(jj[u] << 6) + lane];
#pragma unroll
        for (int u = 0; u < 8; ++u) {
          if ((u & 3) == 0) a0 += ww[u] * vv[u];
          else if ((u & 3) == 1) a1 += ww[u] * vv[u];
          else if ((u & 3) == 2) a2 += ww[u] * vv[u];
          else a3 += ww[u] * vv[u];
        }
      }
      for (; t < n; ++t) a0 += nzv[t] * Vb[(nzi[t] << 6) + lane];
      const float s = ((a0 + a1) + (a2 + a3)) * 0x1p80f;  // pre-scale 2^80
      ctxh[(size_t)((bidx << 10) + i0 + r) * 1024 + (h << 6) + lane] =
          (_Float16)s;
    }
  }
}

// ---------------------------------------------------------------------------
// gemmo_mfma: out = ctx_f16 @ Wo_split * 2^-80 + bo. A = single fp16 plane.
// ---------------------------------------------------------------------------
__global__ __launch_bounds__(256, 2) void gemmo_mfma(
    const _Float16* __restrict__ Ch, const _Float16* __restrict__ Wth,
    const _Float16* __restrict__ Wtl, const float* __restrict__ bias,
    float* __restrict__ out) {
  const int tid = threadIdx.x, lane = tid & 63, wv = tid >> 6;
  const int l15 = lane & 15, lhi = lane >> 4;
  const int n0 = blockIdx.x * 64;
  const int m0 = blockIdx.y * 128 + wv * 32;

  f32x4 aM[2][4], aC[2][4];
#pragma unroll
  for (int i = 0; i < 2; ++i)
#pragma unroll
    for (int j = 0; j < 4; ++j) {
      const f32x4 z = {0.f, 0.f, 0.f, 0.f};
      aM[i][j] = z; aC[i][j] = z;
    }

  const _Float16* xh0 = Ch + (size_t)(m0 + l15) * 1024 + lhi * 8;
  const _Float16* wh0 = Wth + (size_t)(n0 + l15) * 1024 + lhi * 8;
  const _Float16* wl0 = Wtl + (size_t)(n0 + l15) * 1024 + lhi * 8;

#pragma unroll 4
  for (int k0 = 0; k0 < 1024; k0 += 32) {
    f16x8 ah[2], bh[4], bl[4];
#pragma unroll
    for (int mA = 0; mA < 2; ++mA)
      ah[mA] = *(const f16x8*)(xh0 + mA * 16384 + k0);
#pragma unroll
    for (int nB = 0; nB < 4; ++nB) {
      bh[nB] = *(const f16x8*)(wh0 + nB * 16384 + k0);
      bl[nB] = *(const f16x8*)(wl0 + nB * 16384 + k0);
    }
#pragma unroll
    for (int mA = 0; mA < 2; ++mA)
#pragma unroll
      for (int nB = 0; nB < 4; ++nB) {
        aM[mA][nB] = __builtin_amdgcn_mfma_f32_16x16x32_f16(ah[mA], bh[nB], aM[mA][nB], 0, 0, 0);
        aC[mA][nB] = __builtin_amdgcn_mfma_f32_16x16x32_f16(ah[mA], bl[nB], aC[mA][nB], 0, 0, 0);
      }
  }

  const float eps = 4.8828125e-4f;  // 2^-11
  const float unscale = 0x1p-80f;
  float bb[4];
#pragma unroll
  for (int nB = 0; nB < 4; ++nB) bb[nB] = bias[n0 + nB * 16 + l15];
#pragma unroll
  for (int mA = 0; mA < 2; ++mA)
#pragma unroll
    for (int nB = 0; nB < 4; ++nB) {
      const int n = n0 + nB * 16 + l15;
#pragma unroll
      for (int r = 0; r < 4; ++r) {
        const int m = m0 + mA * 16 + lhi * 4 + r;
        out[(size_t)m * 1024 + n] =
            (aM[mA][nB][r] + aC[mA][nB][r] * eps) * unscale + bb[nB];
      }
    }
}

// ---------------------------------------------------------------------------
extern "C" void kernel_launch(void* const* d_in, const int* in_sizes, int n_in,
                              void* d_out, int out_size, void* d_ws,
                              size_t ws_size, hipStream_t stream) {
  (void)in_sizes; (void)n_in; (void)out_size; (void)ws_size;
  const float* hs    = (const float*)d_in[0];
  const float* amask = (const float*)d_in[1];
  const float* Wq    = (const float*)d_in[2];
  const float* bq    = (const float*)d_in[3];
  // d_in[4], d_in[5] = Wk, bk : projected-but-unused in the reference
  const float* Wv    = (const float*)d_in[6];
  const float* bv    = (const float*)d_in[7];
  const float* Wo    = (const float*)d_in[8];
  const float* bo    = (const float*)d_in[9];
  const float* mu    = (const float*)d_in[10];
  const float* prec  = (const float*)d_in[11];
  const float* spw   = (const float*)d_in[12];
  float* out = (float*)d_out;

  // Peak = 15,728,640 floats (proven budget). SINGLE-PASS lifetimes:
  //  [0,4194304)         Xh/Xl (..gemmq) -> Rh/Rl/tneg/lswg (prep..phi3)
  //                      -> P0 [0,3670016) (psi..attn) -> Wot (gemmo)
  //  [3670016,7340032)   P1 (psi..attn)  [overlays dead Qh region]
  //  [4194304,8388608)   Qh/Ql (gemmq..phi3)
  //  [7340032,7405568)   af (psi..attn)
  //  [7405568,7929856)   Wvth (transpose_h..gemmv)  [< 8388608: after phi3]
  //  [8388608,15728640)  Wqt (..gemmq) -> Lt (phi3..psi) ->
  //                      V [8388608,12582912) + ctx fp16 [12582912,14680064)
  float* w = (float*)d_ws;
  _Float16* Xh   = (_Float16*)w;
  _Float16* Xl   = (_Float16*)(w + 2097152);
  _Float16* Rh   = (_Float16*)w;
  _Float16* Rl   = (_Float16*)(w + 229376);
  float*    tneg = w + 458752;
  float*    lswg = w + 465920;
  unsigned short* P0 = (unsigned short*)w;          // [0, 3670016)
  unsigned short* P1 = (unsigned short*)(w + 3670016);  // [3670016, 7340032)
  _Float16* Qh   = (_Float16*)(w + 4194304);
  _Float16* Ql   = (_Float16*)(w + 6291456);
  float*    af   = w + 7340032;                     // [7340032, 7405568)
  _Float16* Wvth = (_Float16*)(w + 7405568);        // [7405568, 7929856)
  _Float16* Wqth = (_Float16*)(w + 8388608);
  _Float16* Wqtl = (_Float16*)(w + 8912896);
  float*    Lt   = w + 8388608;                     // [8388608, 15728640)
  float*    V    = w + 8388608;                     // [8388608, 12582912)
  _Float16* ctxh = (_Float16*)(w + 12582912);       // [12582912, 14680064)
  _Float16* Woth = (_Float16*)w;                    // [0, 524288)
  _Float16* Wotl = (_Float16*)(w + 524288);         // [524288, 1048576)

  split_x<<<dim3(2048), dim3(256), 0, stream>>>(hs, Xh, Xl);
  transpose_split<<<dim3(16, 16), dim3(256), 0, stream>>>(Wq, Wqth, Wqtl);
  gemmq_mfma<<<dim3(16, 32), dim3(256), 0, stream>>>(Xh, Xl, Wqth, Wqtl, bq, Qh, Ql);
  prep_kernel<<<dim3(NP), dim3(256), 0, stream>>>(mu, prec, spw, Rh, Rl, tneg, lswg);
  phi3<<<dim3(256, 8), dim3(256), 0, stream>>>(Qh, Ql, Rh, Rl, tneg, lswg, Lt);
  psi_kernel<<<dim3(1024), dim3(256), 0, stream>>>(Lt, P0, P1, af);
  transpose_h<<<dim3(16, 16), dim3(256), 0, stream>>>(Wv, Wvth);
  gemmv_mfma<<<dim3(16, 32), dim3(256), 0, stream>>>(hs, Wvth, bv, V);
  attn8_kernel<<<dim3(2048), dim3(512), 0, stream>>>(P0, P1, af, V, amask, ctxh);
  transpose_split<<<dim3(16, 16), dim3(256), 0, stream>>>(Wo, Woth, Wotl);
  gemmo_mfma<<<dim3(16, 32), dim3(256), 0, stream>>>(ctxh, Woth, Wotl, bo, out);
}

// Round 21
// 590.558 us; speedup vs baseline: 1.1022x; 1.0072x over previous
//
#include <hip/hip_runtime.h>
#include <cstdint>
#include <cstddef>

// Problem constants (fixed by the reference)
#define NB 4
#define NS 1024
#define ND 1024
#define NH 16
#define NDH 64
#define NP 112
#define NTOPK 64
#define PCH 14      // splats per phi chunk (8 chunks)

typedef _Float16 f16x8 __attribute__((ext_vector_type(8)));
typedef short bf16x8 __attribute__((ext_vector_type(8)));
typedef float f32x4 __attribute__((ext_vector_type(4)));
typedef unsigned short u16x8 __attribute__((ext_vector_type(8)));

// RNE float -> bf16 bits
__device__ __forceinline__ unsigned short bf16r(float f) {
  const unsigned u = __float_as_uint(f);
  return (unsigned short)((u + 0x7FFFu + ((u >> 16) & 1u)) >> 16);
}

// ---------------------------------------------------------------------------
// prep v4: fp64 Cholesky, transposed LDS layout A2[e][t] = A[t][e], trailing
// update parallelized across 4 waves. Bitwise-identical fp64 ops. (r16)
// ---------------------------------------------------------------------------
__global__ __launch_bounds__(256) void prep_kernel(
    const float* __restrict__ mu, const float* __restrict__ prec,
    const float* __restrict__ spw, _Float16* __restrict__ Rh,
    _Float16* __restrict__ Rl, float* __restrict__ tneg,
    float* __restrict__ lswg) {
  __shared__ double A2[64][64];  // 32 KB, A2[e][t] = A[t][e]
  const int p = blockIdx.x;
  const int t = threadIdx.x & 63, q = threadIdx.x >> 6;

  for (int e = q; e < 64; e += 4)
    A2[e][t] = (double)prec[((size_t)p * 64 + e) * 64 + t];  // symmetric read
  __syncthreads();

  for (int k = 0; k < 64; ++k) {
    if (threadIdx.x == k) A2[k][k] = sqrt(A2[k][k]);
    __syncthreads();
    if (q == 0 && t > k) A2[k][t] /= A2[k][k];
    __syncthreads();
    const double lik = A2[k][t];  // meaningful only for t > k (loop guards)
    for (int j = k + 1 + q; j <= t; j += 4)
      A2[j][t] -= lik * A2[k][j];  // distinct (j,t) per thread; reads row k
    __syncthreads();
  }

  for (int d = q; d < 64; d += 4) {
    const float rv = (t >= d) ? (float)A2[d][t] : 0.f;
    const _Float16 h = (_Float16)rv;
    Rh[((size_t)p << 12) + (d << 6) + t] = h;
    Rl[((size_t)p << 12) + (d << 6) + t] =
        (_Float16)((rv - (float)h) * 2048.0f);
  }

  if (q == 0) {
    double s = 0.0;
    for (int e = t; e < 64; ++e) s += A2[t][e] * (double)mu[p * 64 + e];
    tneg[p * 64 + t] = (float)(-s);
  }
  if (threadIdx.x == 0) lswg[p] = 0.5f * logf(spw[p]);
}

// ---------------------------------------------------------------------------
// transpose_split: W[k][n] fp32 (1024x1024) -> Th/Tl [n][k] fp16 split
// ---------------------------------------------------------------------------
__global__ __launch_bounds__(256) void transpose_split(
    const float* __restrict__ W, _Float16* __restrict__ Th,
    _Float16* __restrict__ Tl) {
  __shared__ float T[64][65];
  const int tid = threadIdx.x;
  const int k0 = blockIdx.x * 64, n0 = blockIdx.y * 64;
  const int c = tid & 63, rb = tid >> 6;
#pragma unroll 4
  for (int i = 0; i < 16; ++i) {
    const int r = rb * 16 + i;
    T[r][c] = W[(size_t)(k0 + r) * 1024 + n0 + c];
  }
  __syncthreads();
#pragma unroll 4
  for (int i = 0; i < 16; ++i) {
    const int r = rb * 16 + i;               // local n
    const float v = T[c][r];                 // = W[k0+c][n0+r]
    const _Float16 h = (_Float16)v;
    Th[(size_t)(n0 + r) * 1024 + k0 + c] = h;
    Tl[(size_t)(n0 + r) * 1024 + k0 + c] = (_Float16)((v - (float)h) * 2048.0f);
  }
}

// ---------------------------------------------------------------------------
// transpose_h: W[k][n] fp32 -> Th [n][k] fp16 (hi plane only)
// ---------------------------------------------------------------------------
__global__ __launch_bounds__(256) void transpose_h(
    const float* __restrict__ W, _Float16* __restrict__ Th) {
  __shared__ float T[64][65];
  const int tid = threadIdx.x;
  const int k0 = blockIdx.x * 64, n0 = blockIdx.y * 64;
  const int c = tid & 63, rb = tid >> 6;
#pragma unroll 4
  for (int i = 0; i < 16; ++i) {
    const int r = rb * 16 + i;
    T[r][c] = W[(size_t)(k0 + r) * 1024 + n0 + c];
  }
  __syncthreads();
#pragma unroll 4
  for (int i = 0; i < 16; ++i) {
    const int r = rb * 16 + i;
    Th[(size_t)(n0 + r) * 1024 + k0 + c] = (_Float16)T[c][r];
  }
}

// ---------------------------------------------------------------------------
// gemmq v2: Q = (hs @ Wq + bq) * 0.125 via fp16-split MFMA. A-side split
// computed IN-REGISTER from fp32 hs (bit-identical to the old split_x
// output). Output fp16-split Qh/Ql in [bh][s][d] layout.
// ---------------------------------------------------------------------------
__global__ __launch_bounds__(256, 2) void gemmq_mfma(
    const float* __restrict__ X, const _Float16* __restrict__ Wth,
    const _Float16* __restrict__ Wtl, const float* __restrict__ bias,
    _Float16* __restrict__ QhO, _Float16* __restrict__ QlO) {
  const int tid = threadIdx.x, lane = tid & 63, wv = tid >> 6;
  const int l15 = lane & 15, lhi = lane >> 4;
  const int n0 = blockIdx.x * 64;
  const int m0 = blockIdx.y * 128 + wv * 32;

  f32x4 aM[2][4], aC[2][4];
#pragma unroll
  for (int i = 0; i < 2; ++i)
#pragma unroll
    for (int j = 0; j < 4; ++j) {
      const f32x4 z = {0.f, 0.f, 0.f, 0.f};
      aM[i][j] = z; aC[i][j] = z;
    }

  const float* x0 = X + (size_t)(m0 + l15) * 1024 + lhi * 8;
  const _Float16* wh0 = Wth + (size_t)(n0 + l15) * 1024 + lhi * 8;
  const _Float16* wl0 = Wtl + (size_t)(n0 + l15) * 1024 + lhi * 8;

#pragma unroll 4
  for (int k0 = 0; k0 < 1024; k0 += 32) {
    f16x8 ah[2], al[2], bh[4], bl[4];
#pragma unroll
    for (int mA = 0; mA < 2; ++mA) {
      const float4 a = *(const float4*)(x0 + mA * 16384 + k0);
      const float4 b = *(const float4*)(x0 + mA * 16384 + k0 + 4);
      const float vv[8] = {a.x, a.y, a.z, a.w, b.x, b.y, b.z, b.w};
      f16x8 hv, lv;
#pragma unroll
      for (int j = 0; j < 8; ++j) {
        const _Float16 h = (_Float16)vv[j];
        hv[j] = h;
        lv[j] = (_Float16)((vv[j] - (float)h) * 2048.0f);
      }
      ah[mA] = hv; al[mA] = lv;
    }
#pragma unroll
    for (int nB = 0; nB < 4; ++nB) {
      bh[nB] = *(const f16x8*)(wh0 + nB * 16384 + k0);
      bl[nB] = *(const f16x8*)(wl0 + nB * 16384 + k0);
    }
#pragma unroll
    for (int mA = 0; mA < 2; ++mA)
#pragma unroll
      for (int nB = 0; nB < 4; ++nB) {
        aM[mA][nB] = __builtin_amdgcn_mfma_f32_16x16x32_f16(ah[mA], bh[nB], aM[mA][nB], 0, 0, 0);
        aC[mA][nB] = __builtin_amdgcn_mfma_f32_16x16x32_f16(ah[mA], bl[nB], aC[mA][nB], 0, 0, 0);
        aC[mA][nB] = __builtin_amdgcn_mfma_f32_16x16x32_f16(al[mA], bh[nB], aC[mA][nB], 0, 0, 0);
      }
  }

  const float eps = 4.8828125e-4f;  // 2^-11
  const int h = n0 >> 6;
  float bq[4];
#pragma unroll
  for (int nB = 0; nB < 4; ++nB) bq[nB] = bias[n0 + nB * 16 + l15];
#pragma unroll
  for (int mA = 0; mA < 2; ++mA)
#pragma unroll
    for (int nB = 0; nB < 4; ++nB) {
      const int dd = nB * 16 + l15;
#pragma unroll
      for (int r = 0; r < 4; ++r) {
        const int m = m0 + mA * 16 + lhi * 4 + r;
        const int b = m >> 10, s = m & 1023;
        const float v = (aM[mA][nB][r] + aC[mA][nB][r] * eps + bq[nB]) * 0.125f;
        const _Float16 hh = (_Float16)v;
        const size_t o = ((((size_t)b * NH + h) << 10) + s) * 64 + dd;
        QhO[o] = hh;
        QlO[o] = (_Float16)((v - (float)hh) * 2048.0f);
      }
    }
}

// ---------------------------------------------------------------------------
// gemmv v2: V^T = (hs @ Wv + bv)^T in fp16, layout [bh][d][s] (MFMA B-operand
// layout for the dense PV pass). A converted in-register RNE, B single fp16
// plane. 4 consecutive s packed per 8B store.
// ---------------------------------------------------------------------------
__global__ __launch_bounds__(256, 2) void gemmv_mfma(
    const float* __restrict__ X, const _Float16* __restrict__ Wth,
    const float* __restrict__ bias, _Float16* __restrict__ Vt16) {
  const int tid = threadIdx.x, lane = tid & 63, wv = tid >> 6;
  const int l15 = lane & 15, lhi = lane >> 4;
  const int n0 = blockIdx.x * 64;
  const int m0 = blockIdx.y * 128 + wv * 32;

  f32x4 acc[2][4];
#pragma unroll
  for (int i = 0; i < 2; ++i)
#pragma unroll
    for (int j = 0; j < 4; ++j) {
      const f32x4 z = {0.f, 0.f, 0.f, 0.f};
      acc[i][j] = z;
    }

  const float* x0 = X + (size_t)(m0 + l15) * 1024 + lhi * 8;
  const _Float16* w0 = Wth + (size_t)(n0 + l15) * 1024 + lhi * 8;

#pragma unroll 4
  for (int k0 = 0; k0 < 1024; k0 += 32) {
    f16x8 ah[2], bh[4];
#pragma unroll
    for (int mA = 0; mA < 2; ++mA) {
      const float4 a = *(const float4*)(x0 + mA * 16384 + k0);
      const float4 b = *(const float4*)(x0 + mA * 16384 + k0 + 4);
      f16x8 hv;
      hv[0] = (_Float16)a.x; hv[1] = (_Float16)a.y;
      hv[2] = (_Float16)a.z; hv[3] = (_Float16)a.w;
      hv[4] = (_Float16)b.x; hv[5] = (_Float16)b.y;
      hv[6] = (_Float16)b.z; hv[7] = (_Float16)b.w;
      ah[mA] = hv;
    }
#pragma unroll
    for (int nB = 0; nB < 4; ++nB)
      bh[nB] = *(const f16x8*)(w0 + nB * 16384 + k0);
#pragma unroll
    for (int mA = 0; mA < 2; ++mA)
#pragma unroll
      for (int nB = 0; nB < 4; ++nB)
        acc[mA][nB] = __builtin_amdgcn_mfma_f32_16x16x32_f16(
            ah[mA], bh[nB], acc[mA][nB], 0, 0, 0);
  }

  const int h = n0 >> 6;
  float bb[4];
#pragma unroll
  for (int nB = 0; nB < 4; ++nB) bb[nB] = bias[n0 + nB * 16 + l15];
#pragma unroll
  for (int mA = 0; mA < 2; ++mA)
#pragma unroll
    for (int nB = 0; nB < 4; ++nB) {
      const int dd = nB * 16 + l15;
      const int m0r = m0 + mA * 16 + lhi * 4;       // 4 consecutive tokens
      const int bidx = m0r >> 10, s0 = m0r & 1023;
      const int bh_ = (bidx << 4) + h;
      __align__(8) _Float16 pk[4];
#pragma unroll
      for (int r = 0; r < 4; ++r) pk[r] = (_Float16)(acc[mA][nB][r] + bb[nB]);
      *(float2*)(Vt16 + (((size_t)bh_ * 64 + dd) << 10) + s0) =
          *(const float2*)pk;
    }
}

// ---------------------------------------------------------------------------
// phi v3 (log-domain): ls = 0.5*log(w) - 0.5*||R q + tneg||^2 via MFMA,
// R double-buffered in LDS (XOR-swizzle both sides). Writes Lt[bh][p][s].
// ---------------------------------------------------------------------------
__global__ __launch_bounds__(256, 2) void phi3(
    const _Float16* __restrict__ Qh, const _Float16* __restrict__ Ql,
    const _Float16* __restrict__ Rh, const _Float16* __restrict__ Rl,
    const float* __restrict__ tneg, const float* __restrict__ lswg,
    float* __restrict__ Lt) {
  __shared__ __align__(16) _Float16 RhS[2][4096];
  __shared__ __align__(16) _Float16 RlS[2][4096];
  __shared__ __align__(16) float tns[PCH * 64];
  __shared__ float lsws[PCH];
  const int tid = threadIdx.x, lane = tid & 63, wv = tid >> 6;
  const int l15 = lane & 15, lhi = lane >> 4;
  const int tokbase = blockIdx.x * 256;
  const int tb = tokbase + wv * 64;
  const int pbase = blockIdx.y * PCH;
  const float eps = 4.8828125e-4f;

  for (int i = tid; i < PCH * 16; i += 256)
    ((float4*)tns)[i] = ((const float4*)(tneg + (pbase << 6)))[i];
  if (tid < PCH) lsws[tid] = lswg[pbase + tid];

  f16x8 qb[4][2][2];
#pragma unroll
  for (int T = 0; T < 4; ++T)
#pragma unroll
    for (int c = 0; c < 2; ++c) {
      const size_t off = ((size_t)(tb + T * 16 + l15) << 6) + c * 32 + lhi * 8;
      qb[T][c][0] = *(const f16x8*)(Qh + off);
      qb[T][c][1] = *(const f16x8*)(Ql + off);
    }

  f16x8 sgH[2], sgL[2];
#define PHI_LOAD(p)                                                          \
  {                                                                          \
    const _Float16* rhp = Rh + ((size_t)(pbase + (p)) << 12);                \
    const _Float16* rlp = Rl + ((size_t)(pbase + (p)) << 12);                \
    _Pragma("unroll") for (int j = 0; j < 2; ++j) {                          \
      const int X = tid * 32 + j * 16;                                       \
      const int src = X ^ (((X >> 7) & 7) << 4);                             \
      sgH[j] = *(const f16x8*)((const char*)rhp + src);                      \
      sgL[j] = *(const f16x8*)((const char*)rlp + src);                      \
    }                                                                        \
  }
#define PHI_WRITE(buf)                                                       \
  {                                                                          \
    _Pragma("unroll") for (int j = 0; j < 2; ++j) {                          \
      const int X = tid * 32 + j * 16;                                       \
      *(f16x8*)((char*)&RhS[buf][0] + X) = sgH[j];                           \
      *(f16x8*)((char*)&RlS[buf][0] + X) = sgL[j];                           \
    }                                                                        \
  }

  PHI_LOAD(0)
  PHI_WRITE(0)

  float* ub = Lt + (((size_t)(tokbase >> 10) * NP) << 10);
  const int sbase = (tb & 1023);

  for (int pi = 0; pi < PCH; ++pi) {
    __syncthreads();
    const int buf = pi & 1;
    if (pi + 1 < PCH) PHI_LOAD(pi + 1)

    float sq0 = 0.f, sq1 = 0.f, sq2 = 0.f, sq3 = 0.f;
#pragma unroll
    for (int mt = 0; mt < 4; ++mt) {
      const float4 tv = *(const float4*)&tns[(pi << 6) + mt * 16 + lhi * 4];
      const f32x4 ti = {tv.x, tv.y, tv.z, tv.w};
      const f32x4 z = {0.f, 0.f, 0.f, 0.f};
      f32x4 aM[4], aC[4];
#pragma unroll
      for (int T = 0; T < 4; ++T) { aM[T] = ti; aC[T] = z; }
#pragma unroll
      for (int c = 0; c < 2; ++c) {
        if (mt >= 2 && c == 0) continue;  // upper-tri zero block
        const int row = mt * 16 + l15;
        int bo = row * 128 + c * 64 + lhi * 16;
        bo ^= ((row & 7) << 4);
        const f16x8 ah = *(const f16x8*)((const char*)&RhS[buf][0] + bo);
        const f16x8 al = *(const f16x8*)((const char*)&RlS[buf][0] + bo);
#pragma unroll
        for (int T = 0; T < 4; ++T) {
          aM[T] = __builtin_amdgcn_mfma_f32_16x16x32_f16(ah, qb[T][c][0], aM[T], 0, 0, 0);
          aC[T] = __builtin_amdgcn_mfma_f32_16x16x32_f16(ah, qb[T][c][1], aC[T], 0, 0, 0);
          aC[T] = __builtin_amdgcn_mfma_f32_16x16x32_f16(al, qb[T][c][0], aC[T], 0, 0, 0);
        }
      }
#pragma unroll
      for (int r = 0; r < 4; ++r) {
        float y;
        y = aM[0][r] + aC[0][r] * eps; sq0 += y * y;
        y = aM[1][r] + aC[1][r] * eps; sq1 += y * y;
        y = aM[2][r] + aC[2][r] * eps; sq2 += y * y;
        y = aM[3][r] + aC[3][r] * eps; sq3 += y * y;
      }
    }
    sq0 += __shfl_xor(sq0, 16, 64); sq0 += __shfl_xor(sq0, 32, 64);
    sq1 += __shfl_xor(sq1, 16, 64); sq1 += __shfl_xor(sq1, 32, 64);
    sq2 += __shfl_xor(sq2, 16, 64); sq2 += __shfl_xor(sq2, 32, 64);
    sq3 += __shfl_xor(sq3, 16, 64); sq3 += __shfl_xor(sq3, 32, 64);
    const float sqs = (lhi == 0) ? sq0 : (lhi == 1) ? sq1 : (lhi == 2) ? sq2 : sq3;
    ub[((size_t)(pbase + pi) << 10) + sbase + lane] = lsws[pi] - 0.5f * sqs;

    __syncthreads();
    if (pi + 1 < PCH) PHI_WRITE(buf ^ 1)
  }
#undef PHI_LOAD
#undef PHI_WRITE
}

// ---------------------------------------------------------------------------
// psi v4: FULL pass (1024 blocks, 64 bh). 64 tokens x 4 splat-groups per
// block; ls in 28 registers, one expf pass, TWO exact bf16 planes.
// LDS-staged coalesced u16x8 write-out to token-major [bh][s][112].
// ---------------------------------------------------------------------------
__global__ __launch_bounds__(256) void psi_kernel(
    const float* __restrict__ Lt, unsigned short* __restrict__ P0,
    unsigned short* __restrict__ P1, float* __restrict__ af) {
  __shared__ unsigned short Ls[2][64 * 120];  // 30 KB
  __shared__ float pmax[4][64];
  const int tid = threadIdx.x;
  const int gbh = blockIdx.x >> 4;
  const int s0 = (blockIdx.x & 15) << 6;
  const int tok = tid & 63, pg = tid >> 6;

  const float* col = Lt + ((size_t)gbh * NP + pg * 28) * 1024 + s0 + tok;
  float ls[28];
  float a = -3.4e38f;
#pragma unroll
  for (int j = 0; j < 28; ++j) {
    ls[j] = col[(size_t)j << 10];
    a = fmaxf(a, ls[j]);
  }
  pmax[pg][tok] = a;
  __syncthreads();
  a = fmaxf(fmaxf(pmax[0][tok], pmax[1][tok]),
            fmaxf(pmax[2][tok], pmax[3][tok]));
  if (pg == 0) af[(gbh << 10) + s0 + tok] = a;

  const int rbase = tok * 120 + pg * 28;
#pragma unroll
  for (int jj = 0; jj < 14; ++jj) {
    unsigned short v0[2], v1[2];
#pragma unroll
    for (int e = 0; e < 2; ++e) {
      const float x = expf(ls[jj * 2 + e] - a);
      const unsigned short b0 = bf16r(x);
      const float f0 = __uint_as_float((unsigned)b0 << 16);
      const unsigned short b1 = bf16r((x - f0) * 256.0f);  // exact residual
      if (e == 0) { v0[0] = b0; v0[1] = b1; }
      else        { v1[0] = b0; v1[1] = b1; }
    }
#pragma unroll
    for (int pl = 0; pl < 2; ++pl) {
      ushort2 pk; pk.x = v0[pl]; pk.y = v1[pl];
      *(ushort2*)&Ls[pl][rbase + jj * 2] = pk;
    }
  }
  __syncthreads();

  // coalesced write-out: 896 u16x8 per plane
  const size_t gb = (size_t)((gbh << 10) + s0) * NP;
#pragma unroll 1
  for (int pl = 0; pl < 2; ++pl) {
    unsigned short* dst = (pl == 0 ? P0 : P1) + gb;
    const unsigned short* src = &Ls[pl][0];
    for (int i = tid; i < 896; i += 256) {
      const int t2 = i / 14;
      const int off = (i - t2 * 14) * 8;
      *(u16x8*)(dst + t2 * 112 + off) = *(const u16x8*)(src + t2 * 120 + off);
    }
  }
}

// G-tile fp16 LDS addressing: in-row XOR swizzle spreads the 4 lhi write
// groups across distinct bank octets; read side uses the same row-uniform XOR.
#define GADDR(row, col) \
  (((row) << 11) + ((((col) << 1) ^ ((((row) >> 2) & 3) << 5))))

// ---------------------------------------------------------------------------
// attn9 v2: dense-MFMA PV. Phases per block (32 rows, 2048 blocks):
//  1) Gram G = psi_i psi_j^T via bf16x2 MFMA (pipelined B loads) -> fp16 LDS.
//  2) Per-wave (4 rows): fv/fm fp32, exact top-64 bit-search from
//     MSB(row max), rowsum->inv; write the 2^80-PRE-SCALED normalized fp16
//     row into dead G storage: an = fm*inv*2^80 ~ O(0.1..1) (fp16-safe).
//     [r20 bug: storing unscaled anorm ~1e-25 flushed fp16 to zero.]
//  3) Dense PV: ctx*2^80 = Ascaled @ V via fp16 MFMA -- A-frags from LDS
//     (row=l15, contig-k), B-frags from fp16 V^T [bh][d][s]. No epilogue
//     scale (ctxh already holds ctx*2^80; gemmo unscales by 2^-80).
// XCD grid: bh = ((id>>8)<<3)|(id&7), tile = (id>>3)&31.
// ---------------------------------------------------------------------------
__global__ __launch_bounds__(512) void attn9_kernel(
    const unsigned short* __restrict__ P0, const unsigned short* __restrict__ P1,
    const float* __restrict__ af, const _Float16* __restrict__ Vt16,
    const float* __restrict__ amask, _Float16* __restrict__ ctxh) {
  __shared__ __align__(16) _Float16 Ath[32 * 1024];  // 64 KB: G tile fp16
  __shared__ __align__(16) float eajs[1024];         // 4 KB: exp(a_j)
  __shared__ __align__(16) float msks[1024];         // 4 KB: mask row
  const int tid = threadIdx.x;
  const int id = blockIdx.x;
  const int gbh = ((id >> 8) << 3) | (id & 7);   // 0..63
  const int i0 = ((id >> 3) & 31) * 32;
  const int bidx = gbh >> 4;
  const int h = gbh & 15;
  const int lane = tid & 63, wv = tid >> 6;
  const int l15 = lane & 15, lhi = lane >> 4;
  const float* afb = af + (gbh << 10);
  char* Ab = (char*)Ath;

  eajs[tid] = expf(afb[tid]);
  eajs[tid + 512] = expf(afb[tid + 512]);
  msks[tid] = amask[(bidx << 10) + tid];
  msks[tid + 512] = amask[(bidx << 10) + tid + 512];

  // ---- Phase 1: Gram via bf16x2 MFMA (waves: 2 row-tiles x 4 j-groups) ----
  {
    const unsigned short* Pb0 = P0 + (size_t)(gbh << 10) * NP;
    const unsigned short* Pb1 = P1 + (size_t)(gbh << 10) * NP;
    const bf16x8 zz = {0, 0, 0, 0, 0, 0, 0, 0};
    const int rt = wv >> 2;          // row-tile 0/1
    const int jw = wv & 3;           // j-tile group: 16 tiles each
    bf16x8 A0[4], A1[4];
    {
      const size_t ro = (size_t)(i0 + rt * 16 + l15) * NP;
#pragma unroll
      for (int c = 0; c < 3; ++c) {
        A0[c] = *(const bf16x8*)(Pb0 + ro + c * 32 + lhi * 8);
        A1[c] = *(const bf16x8*)(Pb1 + ro + c * 32 + lhi * 8);
      }
      A0[3] = (lhi < 2) ? *(const bf16x8*)(Pb0 + ro + 96 + lhi * 8) : zz;
      A1[3] = (lhi < 2) ? *(const bf16x8*)(Pb1 + ro + 96 + lhi * 8) : zz;
    }

#define LOADB(dst, Pb, jtv)                                                  \
  {                                                                          \
    const size_t co = (size_t)((jtv) * 16 + l15) * NP;                       \
    _Pragma("unroll") for (int c = 0; c < 3; ++c)                            \
        dst[c] = *(const bf16x8*)(Pb + co + c * 32 + lhi * 8);               \
    dst[3] = (lhi < 2) ? *(const bf16x8*)(Pb + co + 96 + lhi * 8) : zz;      \
  }

    bf16x8 B0c[4], B1c[4], B0n[4];
    LOADB(B0c, Pb0, jw * 16)
    LOADB(B1c, Pb1, jw * 16)

#pragma unroll 1
    for (int jt16 = 0; jt16 < 16; ++jt16) {
      const int jt = jw * 16 + jt16;
      if (jt16 < 15) LOADB(B0n, Pb0, jt + 1)  // prefetch next hi plane
      f32x4 g0 = {0.f, 0.f, 0.f, 0.f};
      f32x4 g1a = {0.f, 0.f, 0.f, 0.f}, g1b = {0.f, 0.f, 0.f, 0.f};
      __builtin_amdgcn_s_setprio(1);
#pragma unroll
      for (int c = 0; c < 4; ++c) {
        g0  = __builtin_amdgcn_mfma_f32_16x16x32_bf16(A0[c], B0c[c], g0, 0, 0, 0);
        g1a = __builtin_amdgcn_mfma_f32_16x16x32_bf16(A0[c], B1c[c], g1a, 0, 0, 0);
        g1b = __builtin_amdgcn_mfma_f32_16x16x32_bf16(A1[c], B0c[c], g1b, 0, 0, 0);
      }
      __builtin_amdgcn_s_setprio(0);
#pragma unroll
      for (int r = 0; r < 4; ++r) {
        const float g = fmaxf(g0[r] + (g1a[r] + g1b[r]) * 0.00390625f, 0.f);
        *(_Float16*)(Ab + GADDR(rt * 16 + lhi * 4 + r, jt * 16 + l15)) =
            (_Float16)g;
      }
      if (jt16 < 15) {
        LOADB(B1c, Pb1, jt + 1)  // lo plane: hides under next g0 chain
#pragma unroll
        for (int c = 0; c < 4; ++c) B0c[c] = B0n[c];
      }
    }
#undef LOADB
  }
  __syncthreads();

  // ---- Phase 2: per-wave 4 rows: fv, top-64 thr, inv, scaled write ----
  {
#pragma unroll
    for (int rr = 0; rr < 4; ++rr) {
      const int r = wv * 4 + rr;
      const float eai = expf(afb[i0 + r]);
      float fv[16], fm[16];
      float mx = 0.f;
#pragma unroll
      for (int k = 0; k < 16; ++k) {
        const int j = k * 64 + lane;
        const float gv = (float)*(const _Float16*)(Ab + GADDR(r, j));
        fv[k] = eai * (eajs[j] * gv);
        fm[k] = fv[k] * msks[j];
        mx = fmaxf(mx, fv[k]);
      }
      // wave max -> start bit (skipped candidates all have cnt==0)
#pragma unroll
      for (int off = 32; off > 0; off >>= 1) mx = fmaxf(mx, __shfl_xor(mx, off, 64));
      const unsigned mu = __float_as_uint(mx);
      const int startbit = (mu == 0u) ? 0 : (31 - __clz(mu));
      unsigned c = 0u;
      for (int bit = startbit; bit >= 0; --bit) {
        const unsigned cand = c | (1u << bit);
        int cnt = 0;
#pragma unroll
        for (int k = 0; k < 16; ++k)
          cnt += (int)__popcll(__ballot(__float_as_uint(fv[k]) >= cand));
        if (cnt >= NTOPK) {
          c = cand;
          if (cnt == NTOPK) break;
        }
      }
      const float thr = __uint_as_float(c);
      float ssum = 0.f;
#pragma unroll
      for (int k = 0; k < 16; ++k) ssum += (fv[k] >= thr) ? fm[k] : 0.f;
#pragma unroll
      for (int off = 32; off > 0; off >>= 1) ssum += __shfl_xor(ssum, off, 64);
      const float inv = 1.0f / fmaxf(ssum, 1e-12f);
      const float invs = inv * 0x1p80f;  // pre-scale: keeps fp16 in range

      // overwrite this row of the G tile with the scaled normalized fp16 row
#pragma unroll
      for (int k = 0; k < 16; ++k) {
        const int j = k * 64 + lane;
        const float an = (fv[k] >= thr) ? fm[k] * invs : 0.f;
        *(_Float16*)(Ab + GADDR(r, j)) = (_Float16)an;
      }
    }
  }
  __syncthreads();

  // ---- Phase 3: dense PV: ctx*2^80 = Ascaled @ V via fp16 MFMA ----
  {
    const int rt = wv >> 2;          // row-tile 0/1 (rows rt*16 .. +15)
    const int ct = wv & 3;           // col-tile (d = ct*16 .. +15)
    const _Float16* Vb = Vt16 + (((size_t)gbh * 64 + ct * 16 + l15) << 10);
    f32x4 acc = {0.f, 0.f, 0.f, 0.f};
#pragma unroll 4
    for (int c = 0; c < 32; ++c) {
      const int kb = c * 32 + lhi * 8;
      const f16x8 a = *(const f16x8*)(Ab + GADDR(rt * 16 + l15, kb));
      const f16x8 b = *(const f16x8*)(Vb + kb);
      acc = __builtin_amdgcn_mfma_f32_16x16x32_f16(a, b, acc, 0, 0, 0);
    }
#pragma unroll
    for (int r = 0; r < 4; ++r) {
      const int row = i0 + rt * 16 + lhi * 4 + r;
      ctxh[(size_t)((bidx << 10) + row) * 1024 + (h << 6) + ct * 16 + l15] =
          (_Float16)acc[r];
    }
  }
}

// ---------------------------------------------------------------------------
// gemmo_mfma: out = ctx_f16 @ Wo_split * 2^-80 + bo. A = single fp16 plane.
// ---------------------------------------------------------------------------
__global__ __launch_bounds__(256, 2) void gemmo_mfma(
    const _Float16* __restrict__ Ch, const _Float16* __restrict__ Wth,
    const _Float16* __restrict__ Wtl, const float* __restrict__ bias,
    float* __restrict__ out) {
  const int tid = threadIdx.x, lane = tid & 63, wv = tid >> 6;
  const int l15 = lane & 15, lhi = lane >> 4;
  const int n0 = blockIdx.x * 64;
  const int m0 = blockIdx.y * 128 + wv * 32;

  f32x4 aM[2][4], aC[2][4];
#pragma unroll
  for (int i = 0; i < 2; ++i)
#pragma unroll
    for (int j = 0; j < 4; ++j) {
      const f32x4 z = {0.f, 0.f, 0.f, 0.f};
      aM[i][j] = z; aC[i][j] = z;
    }

  const _Float16* xh0 = Ch + (size_t)(m0 + l15) * 1024 + lhi * 8;
  const _Float16* wh0 = Wth + (size_t)(n0 + l15) * 1024 + lhi * 8;
  const _Float16* wl0 = Wtl + (size_t)(n0 + l15) * 1024 + lhi * 8;

#pragma unroll 4
  for (int k0 = 0; k0 < 1024; k0 += 32) {
    f16x8 ah[2], bh[4], bl[4];
#pragma unroll
    for (int mA = 0; mA < 2; ++mA)
      ah[mA] = *(const f16x8*)(xh0 + mA * 16384 + k0);
#pragma unroll
    for (int nB = 0; nB < 4; ++nB) {
      bh[nB] = *(const f16x8*)(wh0 + nB * 16384 + k0);
      bl[nB] = *(const f16x8*)(wl0 + nB * 16384 + k0);
    }
#pragma unroll
    for (int mA = 0; mA < 2; ++mA)
#pragma unroll
      for (int nB = 0; nB < 4; ++nB) {
        aM[mA][nB] = __builtin_amdgcn_mfma_f32_16x16x32_f16(ah[mA], bh[nB], aM[mA][nB], 0, 0, 0);
        aC[mA][nB] = __builtin_amdgcn_mfma_f32_16x16x32_f16(ah[mA], bl[nB], aC[mA][nB], 0, 0, 0);
      }
  }

  const float eps = 4.8828125e-4f;  // 2^-11
  const float unscale = 0x1p-80f;
  float bb[4];
#pragma unroll
  for (int nB = 0; nB < 4; ++nB) bb[nB] = bias[n0 + nB * 16 + l15];
#pragma unroll
  for (int mA = 0; mA < 2; ++mA)
#pragma unroll
    for (int nB = 0; nB < 4; ++nB) {
      const int n = n0 + nB * 16 + l15;
#pragma unroll
      for (int r = 0; r < 4; ++r) {
        const int m = m0 + mA * 16 + lhi * 4 + r;
        out[(size_t)m * 1024 + n] =
            (aM[mA][nB][r] + aC[mA][nB][r] * eps) * unscale + bb[nB];
      }
    }
}

// ---------------------------------------------------------------------------
extern "C" void kernel_launch(void* const* d_in, const int* in_sizes, int n_in,
                              void* d_out, int out_size, void* d_ws,
                              size_t ws_size, hipStream_t stream) {
  (void)in_sizes; (void)n_in; (void)out_size; (void)ws_size;
  const float* hs    = (const float*)d_in[0];
  const float* amask = (const float*)d_in[1];
  const float* Wq    = (const float*)d_in[2];
  const float* bq    = (const float*)d_in[3];
  // d_in[4], d_in[5] = Wk, bk : projected-but-unused in the reference
  const float* Wv    = (const float*)d_in[6];
  const float* bv    = (const float*)d_in[7];
  const float* Wo    = (const float*)d_in[8];
  const float* bo    = (const float*)d_in[9];
  const float* mu    = (const float*)d_in[10];
  const float* prec  = (const float*)d_in[11];
  const float* spw   = (const float*)d_in[12];
  float* out = (float*)d_out;

  // Peak = 15,728,640 floats (proven budget). SINGLE-PASS lifetimes:
  //  [0,466048)          Rh/Rl/tneg/lswg (prep..phi3)
  //  [0,3670016)         P0 (psi..attn) -> Wot (gemmo)
  //  [3670016,7340032)   P1 (psi..attn)  [overlays dead Qh region]
  //  [4194304,8388608)   Qh/Ql (gemmq..phi3)
  //  [7340032,7405568)   af (psi..attn)
  //  [7405568,7929856)   Wvth (transpose_h..gemmv)
  //  [8388608,15728640)  Wqt (..gemmq) -> Lt (phi3..psi) ->
  //                      Vt16 fp16 [8388608,10485760) + ctx [12582912,14680064)
  float* w = (float*)d_ws;
  _Float16* Rh   = (_Float16*)w;
  _Float16* Rl   = (_Float16*)(w + 229376);
  float*    tneg = w + 458752;
  float*    lswg = w + 465920;
  unsigned short* P0 = (unsigned short*)w;          // [0, 3670016)
  unsigned short* P1 = (unsigned short*)(w + 3670016);  // [3670016, 7340032)
  _Float16* Qh   = (_Float16*)(w + 4194304);
  _Float16* Ql   = (_Float16*)(w + 6291456);
  float*    af   = w + 7340032;                     // [7340032, 7405568)
  _Float16* Wvth = (_Float16*)(w + 7405568);        // [7405568, 7929856)
  _Float16* Wqth = (_Float16*)(w + 8388608);
  _Float16* Wqtl = (_Float16*)(w + 8912896);
  float*    Lt   = w + 8388608;                     // [8388608, 15728640)
  _Float16* Vt16 = (_Float16*)(w + 8388608);        // [8388608, 10485760)
  _Float16* ctxh = (_Float16*)(w + 12582912);       // [12582912, 14680064)
  _Float16* Woth = (_Float16*)w;                    // [0, 524288)
  _Float16* Wotl = (_Float16*)(w + 524288);         // [524288, 1048576)

  transpose_split<<<dim3(16, 16), dim3(256), 0, stream>>>(Wq, Wqth, Wqtl);
  gemmq_mfma<<<dim3(16, 32), dim3(256), 0, stream>>>(hs, Wqth, Wqtl, bq, Qh, Ql);
  prep_kernel<<<dim3(NP), dim3(256), 0, stream>>>(mu, prec, spw, Rh, Rl, tneg, lswg);
  phi3<<<dim3(256, 8), dim3(256), 0, stream>>>(Qh, Ql, Rh, Rl, tneg, lswg, Lt);
  psi_kernel<<<dim3(1024), dim3(256), 0, stream>>>(Lt, P0, P1, af);
  transpose_h<<<dim3(16, 16), dim3(256), 0, stream>>>(Wv, Wvth);
  gemmv_mfma<<<dim3(16, 32), dim3(256), 0, stream>>>(hs, Wvth, bv, Vt16);
  attn9_kernel<<<dim3(2048), dim3(512), 0, stream>>>(P0, P1, af, Vt16, amask, ctxh);
  transpose_split<<<dim3(16, 16), dim3(256), 0, stream>>>(Wo, Woth, Wotl);
  gemmo_mfma<<<dim3(16, 32), dim3(256), 0, stream>>>(ctxh, Woth, Wotl, bo, out);
}